// Round 11
// baseline (1999.243 us; speedup 1.0000x reference)
//
#include <hip/hip_runtime.h>
#include <hip/hip_bf16.h>
#include <cstdint>
#include <cstddef>

#define VOCAB 32000
#define HIDDEN 1024
#define BATCH 32
#define SEQ 128

typedef __attribute__((ext_vector_type(8))) short short8v;
typedef __attribute__((ext_vector_type(4))) float float4v;
typedef __attribute__((ext_vector_type(2))) unsigned int uint2v;

__device__ __forceinline__ unsigned short f2bf(float f) {
    unsigned int x = __float_as_uint(f);
    unsigned int r = x + 0x7fffu + ((x >> 16) & 1u);  // RNE
    return (unsigned short)(r >> 16);
}

// ---------------- pre-conversion: transpose fp32 [rows][cols] -> bf16 [cols][rows] ----------------
__global__ __launch_bounds__(256) void k_transpose_bf(const float* __restrict__ in,
                                                      unsigned short* __restrict__ out,
                                                      int cols, int rows) {
    __shared__ float tile[64][65];
    const int jb = blockIdx.x;
    const int kb = blockIdx.y;
    const int t  = threadIdx.x;
    const int c  = t & 63;
    const int r0 = (t >> 6) * 16;
#pragma unroll
    for (int i = 0; i < 16; i++) {
        int r = r0 + i;
        tile[r][c] = in[(size_t)(kb * 64 + r) * cols + jb * 64 + c];
    }
    __syncthreads();
#pragma unroll
    for (int i = 0; i < 16; i++) {
        int r = r0 + i;
        out[(size_t)(jb * 64 + r) * rows + kb * 64 + c] = f2bf(tile[c][r]);
    }
}

// ---------------- fused persistent kernel: recurrence workers + streaming GEMM ----------------
// 384 blocks x 256 threads, LDS union 66 KB -> 2 blocks/CU -> ALL 384 resident under
// any placement (no dispatch-order assumption; deadlock-free by capacity).
//
// Blocks 0..127  = WORKERS (wave 0 only; threads 64..255 exit): the r9-proven
//   recurrence protocol: weights wr/wz in LDS, W_hh streamed per step (r8-proven),
//   rotating write-once exchange buffers (rh->rhall[t], h->hall[t]), WT data stores
//   + vmcnt drain + direct producer-push tags into per-consumer mailbox rows
//   (agent scope). After phase-B publish, lane 0 bumps done[t] (agent atomicAdd).
// Blocks 128..383 = GEMM (4 waves): out[4096][32000] = hall @ bt^T + b_o, 128x128
//   tiles assigned mb-major (t8 = gbid + 256k), each tile gated on
//   done[4*mb+3] == 128 -- hall rows for the tile are final at MALL before any
//   read (write-once + first-touch-after-gate, the r5-r9-proven coherence rule).
//   Gate polling: block leader probes the done counter (s_sleep(32) cadence),
//   broadcasts via an LDS word -- 1 fabric probe per block per ~2k cy, on lines
//   disjoint from the workers' mailboxes.
// All spins watchdog-capped: failure = wrong absmax, never a hang.

#define WAIT_VM0 asm volatile("s_waitcnt vmcnt(0)" ::: "memory")
#define LGKM0    asm volatile("s_waitcnt lgkmcnt(0)" ::: "memory")

#define ST8_WT(P, V) \
    asm volatile("global_store_dwordx2 %0, %1, off sc0 sc1" ::"v"(P), "v"(V) : "memory")

__device__ __forceinline__ void row_poll(const unsigned int* row, unsigned int tag) {
    const unsigned int* p = row + (threadIdx.x & 63);
    int guard = 0;
    while (true) {
        unsigned int v = __hip_atomic_load(p, __ATOMIC_RELAXED, __HIP_MEMORY_SCOPE_AGENT);
        if (__all((int)(v >= tag))) break;
        if (++guard > 8192) break;  // watchdog (never trips when healthy — r9)
        __builtin_amdgcn_s_sleep(1);
    }
}

__device__ __forceinline__ void gload_lds16(const void* g, void* l) {
    __builtin_amdgcn_global_load_lds((const __attribute__((address_space(1))) void*)g,
                                     (__attribute__((address_space(3))) void*)l, 16, 0, 0);
}

typedef struct {
    short8v wlds[2][32][64];        // 64 KB: W_hr, W_hz B-fragments
    unsigned short pack[16 * 16];   // 512 B exchange tile
} WorkerSM;
typedef struct {
    unsigned short As[128 * 64];    // 16 KB
    unsigned short Bs[128 * 64];    // 16 KB
    unsigned int ready;             // highest cleared mb+1
} GemmSM;

__global__ __launch_bounds__(256, 1) void k_fused(const int* __restrict__ x,
                                                  const float* __restrict__ state,
                                                  const unsigned short* __restrict__ wrt,
                                                  const unsigned short* __restrict__ wzt,
                                                  const unsigned short* __restrict__ wht,
                                                  const float* __restrict__ W_xr, const float* __restrict__ b_r,
                                                  const float* __restrict__ W_xz, const float* __restrict__ b_z,
                                                  const float* __restrict__ W_xh, const float* __restrict__ b_h,
                                                  unsigned short* __restrict__ hall,   // [128][32][1024]
                                                  unsigned short* __restrict__ rhall,  // [128][32][1024]
                                                  float* __restrict__ hstate_out,      // [32][1024]
                                                  unsigned int* __restrict__ mbox,     // [2][64][64]
                                                  unsigned int* __restrict__ done,     // [128]
                                                  const unsigned short* __restrict__ bt,  // [32000][1024]
                                                  const float* __restrict__ bo,
                                                  float* __restrict__ out) {
    __shared__ union { WorkerSM w; GemmSM g; } sm;
    const int bid = blockIdx.x;

    if (bid < 128) {
        // ================= WORKER =================
        if (threadIdx.x >= 64) return;
        const int g   = bid >> 6;
        const int jsl = bid & 63;
        const int j0  = jsl * 16;
        const int b0  = g * 16;
        const int l   = threadIdx.x;
        const int llo = l & 15;
        const int lhi = l >> 4;
        const int jg  = j0 + llo;

        unsigned int* gm          = mbox + g * 64 * 64;
        const unsigned int* myrow = gm + jsl * 64;
        unsigned int* pushtgt     = gm + l * 64 + jsl;

        // one-time: wr/wz fragments -> LDS
#pragma unroll
        for (int i = 0; i < 32; i++) {
            const size_t off = (size_t)jg * HIDDEN + i * 32 + lhi * 8;
            sm.w.wlds[0][i][l] = *(const short8v*)&wrt[off];
            sm.w.wlds[1][i][l] = *(const short8v*)&wzt[off];
        }
        const float brv = b_r[jg], bzv = b_z[jg], bhv = b_h[jg];
        float4v hO;
#pragma unroll
        for (int q = 0; q < 4; q++) hO[q] = state[(b0 + 4 * lhi + q) * HIDDEN + jg];
        LGKM0;

        for (int t = 0; t < SEQ; t++) {
            unsigned short* rhp = rhall + (size_t)t * BATCH * HIDDEN;
            unsigned short* hp  = hall + (size_t)t * BATCH * HIDDEN;

            // embedding gathers issued BEFORE the poll
            int tok[4];
#pragma unroll
            for (int q = 0; q < 4; q++) tok[q] = x[(size_t)(b0 + 4 * lhi + q) * SEQ + t];
            float xr[4], xz[4], xh[4];
#pragma unroll
            for (int q = 0; q < 4; q++) {
                xr[q] = W_xr[(size_t)tok[q] * HIDDEN + jg];
                xz[q] = W_xz[(size_t)tok[q] * HIDDEN + jg];
                xh[q] = W_xh[(size_t)tok[q] * HIDDEN + jg];
            }

            // ---- Phase A: wait h(t-1), compute r,z ----
            short8v af[32];
            if (t == 0) {
#pragma unroll
                for (int i = 0; i < 32; i++) {
                    const float* sp = &state[(size_t)(b0 + llo) * HIDDEN + i * 32 + lhi * 8];
                    short8v v;
#pragma unroll
                    for (int e = 0; e < 8; e++) v[e] = (short)f2bf(sp[e]);
                    af[i] = v;
                }
            } else {
                row_poll(myrow, 2u * (unsigned)t);
                const unsigned short* hprev = hall + (size_t)(t - 1) * BATCH * HIDDEN;
#pragma unroll
                for (int i = 0; i < 32; i++)
                    af[i] = *(const short8v*)&hprev[(b0 + llo) * HIDDEN + i * 32 + lhi * 8];
            }

            float4v aR0 = {0.f, 0.f, 0.f, 0.f}, aR1 = {0.f, 0.f, 0.f, 0.f};
            float4v aZ0 = {0.f, 0.f, 0.f, 0.f}, aZ1 = {0.f, 0.f, 0.f, 0.f};
#pragma unroll
            for (int i = 0; i < 32; i += 2) {
                aR0 = __builtin_amdgcn_mfma_f32_16x16x32_bf16(af[i],     sm.w.wlds[0][i][l],     aR0, 0, 0, 0);
                aZ0 = __builtin_amdgcn_mfma_f32_16x16x32_bf16(af[i],     sm.w.wlds[1][i][l],     aZ0, 0, 0, 0);
                aR1 = __builtin_amdgcn_mfma_f32_16x16x32_bf16(af[i + 1], sm.w.wlds[0][i + 1][l], aR1, 0, 0, 0);
                aZ1 = __builtin_amdgcn_mfma_f32_16x16x32_bf16(af[i + 1], sm.w.wlds[1][i + 1][l], aZ1, 0, 0, 0);
            }

            float4v zv;
#pragma unroll
            for (int q = 0; q < 4; q++) {
                float sr = aR0[q] + aR1[q] + xr[q] + brv;
                float sz = aZ0[q] + aZ1[q] + xz[q] + bzv;
                float rv = 1.f / (1.f + __expf(-sr));
                zv[q]    = 1.f / (1.f + __expf(-sz));
                sm.w.pack[(4 * lhi + q) * 16 + llo] = f2bf(rv * hO[q]);
            }
            LGKM0;
            __builtin_amdgcn_wave_barrier();
            {   // publish rh tile
                uint2v v = *(const uint2v*)&sm.w.pack[(l >> 2) * 16 + (l & 3) * 4];
                ST8_WT(&rhp[(b0 + (l >> 2)) * HIDDEN + j0 + (l & 3) * 4], v);
                WAIT_VM0;
                __hip_atomic_store(pushtgt, 2u * (unsigned)t + 1u, __ATOMIC_RELAXED,
                                   __HIP_MEMORY_SCOPE_AGENT);
            }

            // stream W_hh for this step (hides under the phase-B wait)
            short8v wh[32];
#pragma unroll
            for (int i = 0; i < 32; i++)
                wh[i] = *(const short8v*)&wht[(size_t)jg * HIDDEN + i * 32 + lhi * 8];

            // ---- Phase B: wait rh, compute candidate + update ----
            row_poll(myrow, 2u * (unsigned)t + 1u);

            short8v ar[32];
#pragma unroll
            for (int i = 0; i < 32; i++)
                ar[i] = *(const short8v*)&rhp[(b0 + llo) * HIDDEN + i * 32 + lhi * 8];

            float4v aC0 = {0.f, 0.f, 0.f, 0.f}, aC1 = {0.f, 0.f, 0.f, 0.f};
#pragma unroll
            for (int i = 0; i < 32; i += 2) {
                aC0 = __builtin_amdgcn_mfma_f32_16x16x32_bf16(ar[i],     wh[i],     aC0, 0, 0, 0);
                aC1 = __builtin_amdgcn_mfma_f32_16x16x32_bf16(ar[i + 1], wh[i + 1], aC1, 0, 0, 0);
            }
#pragma unroll
            for (int q = 0; q < 4; q++) {
                float a = aC0[q] + aC1[q] + xh[q] + bhv;
                a = fminf(15.f, fmaxf(-15.f, a));
                float e2   = __expf(2.f * a);
                float cand = (e2 - 1.f) / (e2 + 1.f);
                float hn   = zv[q] * hO[q] + (1.f - zv[q]) * cand;
                hO[q]      = hn;
                sm.w.pack[(4 * lhi + q) * 16 + llo] = f2bf(hn);
            }
            LGKM0;
            __builtin_amdgcn_wave_barrier();
            {   // publish h tile into hall[t]; then notify consumers + GEMM
                uint2v v = *(const uint2v*)&sm.w.pack[(l >> 2) * 16 + (l & 3) * 4];
                ST8_WT(&hp[(b0 + (l >> 2)) * HIDDEN + j0 + (l & 3) * 4], v);
                WAIT_VM0;
                __hip_atomic_store(pushtgt, 2u * (unsigned)t + 2u, __ATOMIC_RELAXED,
                                   __HIP_MEMORY_SCOPE_AGENT);
                if (l == 0)
                    __hip_atomic_fetch_add(&done[t], 1u, __ATOMIC_RELAXED,
                                           __HIP_MEMORY_SCOPE_AGENT);
            }
        }

#pragma unroll
        for (int q = 0; q < 4; q++)
            hstate_out[(b0 + 4 * lhi + q) * HIDDEN + jg] = hO[q];
        return;
    }

    // ================= GEMM =================
    const int gbid = bid - 128;  // 0..255
    const int tid  = threadIdx.x;
    if (tid == 0)
        __hip_atomic_store(&sm.g.ready, 0u, __ATOMIC_RELAXED, __HIP_MEMORY_SCOPE_WORKGROUP);
    __syncthreads();

    const int lane = tid & 63;
    const int w    = tid >> 6;
    const int wm   = w >> 1, wn = w & 1;

    for (int t8 = gbid; t8 < 8000; t8 += 256) {
        const int mb = t8 / 250;
        const int nb = t8 % 250;

        // gate: hall rows for this mb final once done[4mb+3]==128 (leader poll + LDS bcast)
        {
            int guard = 0;
            while (true) {
                unsigned int r = __hip_atomic_load(&sm.g.ready, __ATOMIC_RELAXED,
                                                   __HIP_MEMORY_SCOPE_WORKGROUP);
                if (r > (unsigned)mb) break;
                if (tid == 0) {
                    unsigned int d = __hip_atomic_load(&done[4 * mb + 3], __ATOMIC_RELAXED,
                                                       __HIP_MEMORY_SCOPE_AGENT);
                    if (d >= 128u)
                        __hip_atomic_store(&sm.g.ready, (unsigned)(mb + 1), __ATOMIC_RELAXED,
                                           __HIP_MEMORY_SCOPE_WORKGROUP);
                    else
                        __builtin_amdgcn_s_sleep(32);
                } else {
                    __builtin_amdgcn_s_sleep(8);
                }
                if (++guard > (1 << 18)) break;  // watchdog
            }
        }

        const int row0 = mb * 128, col0 = nb * 128;
        float4v acc[4][4];
#pragma unroll
        for (int i = 0; i < 4; i++)
#pragma unroll
            for (int j = 0; j < 4; j++) acc[i][j] = float4v{0.f, 0.f, 0.f, 0.f};

        for (int kt = 0; kt < HIDDEN / 64; kt++) {
#pragma unroll
            for (int i = 0; i < 4; i++) {
                int s   = i * 256 + tid;
                int row = s >> 3;
                int off = (s & 7) * 8;
                gload_lds16(hall + (size_t)(row0 + row) * HIDDEN + kt * 64 + off, &sm.g.As[s * 8]);
                gload_lds16(bt + (size_t)(col0 + row) * HIDDEN + kt * 64 + off, &sm.g.Bs[s * 8]);
            }
            __syncthreads();
#pragma unroll
            for (int kk = 0; kk < 2; kk++) {
                short8v af[4], bf[4];
#pragma unroll
                for (int i = 0; i < 4; i++) {
                    int ar = wm * 64 + i * 16 + (lane & 15);
                    af[i] = *(short8v*)&sm.g.As[ar * 64 + kk * 32 + (lane >> 4) * 8];
                    int br = wn * 64 + i * 16 + (lane & 15);
                    bf[i] = *(short8v*)&sm.g.Bs[br * 64 + kk * 32 + (lane >> 4) * 8];
                }
#pragma unroll
                for (int i = 0; i < 4; i++)
#pragma unroll
                    for (int j = 0; j < 4; j++)
                        acc[i][j] = __builtin_amdgcn_mfma_f32_16x16x32_bf16(af[i], bf[j], acc[i][j], 0, 0, 0);
            }
            __syncthreads();
        }
#pragma unroll
        for (int i = 0; i < 4; i++) {
            int grow = row0 + wm * 64 + i * 16 + (lane >> 4) * 4;
#pragma unroll
            for (int j = 0; j < 4; j++) {
                int gcol   = col0 + wn * 64 + j * 16 + (lane & 15);
                float bias = bo[gcol];
#pragma unroll
                for (int r = 0; r < 4; r++) {
                    out[(size_t)(grow + r) * VOCAB + gcol] = acc[i][j][r] + bias;
                }
            }
        }
    }
}

// ---------------- host ----------------

extern "C" void kernel_launch(void* const* d_in, const int* in_sizes, int n_in,
                              void* d_out, int out_size, void* d_ws, size_t ws_size,
                              hipStream_t stream) {
    const int*   x     = (const int*)d_in[0];
    const float* state = (const float*)d_in[1];
    const float* W_xr  = (const float*)d_in[2];
    const float* W_hr  = (const float*)d_in[3];
    const float* b_r   = (const float*)d_in[4];
    const float* W_xz  = (const float*)d_in[5];
    const float* W_hz  = (const float*)d_in[6];
    const float* b_z   = (const float*)d_in[7];
    const float* W_xh  = (const float*)d_in[8];
    const float* W_hh  = (const float*)d_in[9];
    const float* b_h   = (const float*)d_in[10];
    const float* W_ho  = (const float*)d_in[11];
    const float* b_o   = (const float*)d_in[12];

    float* out    = (float*)d_out;
    float* hstate = out + (size_t)SEQ * BATCH * VOCAB;

    // ws layout (bytes):
    //   0        : hall  bf16 [128][32][1024]   8,388,608  (= GEMM A matrix)
    //   8388608  : rhall bf16 [128][32][1024]   8,388,608
    //   16777216 : bt    bf16 [32000][1024]    65,536,000
    //   82313216 : wrt   bf16 [1024][1024]      2,097,152
    //   84410368 : wzt   bf16                   2,097,152
    //   86507520 : wht   bf16                   2,097,152
    //   88604672 : mbox  u32  [2][64][64]          32,768
    //   88637440 : done  u32  [128]                  512    total 88,637,952
    char* ws = (char*)d_ws;
    unsigned short* hall  = (unsigned short*)ws;
    unsigned short* rhall = (unsigned short*)(ws + 8388608);
    unsigned short* bt    = (unsigned short*)(ws + 16777216);
    unsigned short* wrt   = (unsigned short*)(ws + 82313216);
    unsigned short* wzt   = (unsigned short*)(ws + 84410368);
    unsigned short* wht   = (unsigned short*)(ws + 86507520);
    unsigned int*   mbox  = (unsigned int*)(ws + 88604672);
    unsigned int*   done  = (unsigned int*)(ws + 88637440);

    hipMemsetAsync(mbox, 0, 32768 + 512, stream);
    k_transpose_bf<<<dim3(16, 16), 256, 0, stream>>>(W_hr, wrt, HIDDEN, HIDDEN);
    k_transpose_bf<<<dim3(16, 16), 256, 0, stream>>>(W_hz, wzt, HIDDEN, HIDDEN);
    k_transpose_bf<<<dim3(16, 16), 256, 0, stream>>>(W_hh, wht, HIDDEN, HIDDEN);
    k_transpose_bf<<<dim3(500, 16), 256, 0, stream>>>(W_ho, bt, VOCAB, HIDDEN);

    k_fused<<<384, 256, 0, stream>>>(x, state, wrt, wzt, wht, W_xr, b_r, W_xz, b_z,
                                     W_xh, b_h, hall, rhall, hstate, mbox, done,
                                     bt, b_o, out);
}

// Round 12
// 1287.790 us; speedup vs baseline: 1.5525x; 1.5525x over previous
//
#include <hip/hip_runtime.h>
#include <hip/hip_bf16.h>
#include <cstdint>
#include <cstddef>

#define VOCAB 32000
#define HIDDEN 1024
#define BATCH 32
#define SEQ 128

typedef __attribute__((ext_vector_type(8))) short short8v;
typedef __attribute__((ext_vector_type(4))) float float4v;
typedef __attribute__((ext_vector_type(2))) unsigned int uint2v;

__device__ __forceinline__ unsigned short f2bf(float f) {
    unsigned int x = __float_as_uint(f);
    unsigned int r = x + 0x7fffu + ((x >> 16) & 1u);  // RNE
    return (unsigned short)(r >> 16);
}

// ---------------- pre-conversion: transpose fp32 [rows][cols] -> bf16 [cols][rows] ----------------
__global__ __launch_bounds__(256) void k_transpose_bf(const float* __restrict__ in,
                                                      unsigned short* __restrict__ out,
                                                      int cols, int rows) {
    __shared__ float tile[64][65];
    const int jb = blockIdx.x;
    const int kb = blockIdx.y;
    const int t  = threadIdx.x;
    const int c  = t & 63;
    const int r0 = (t >> 6) * 16;
#pragma unroll
    for (int i = 0; i < 16; i++) {
        int r = r0 + i;
        tile[r][c] = in[(size_t)(kb * 64 + r) * cols + jb * 64 + c];
    }
    __syncthreads();
#pragma unroll
    for (int i = 0; i < 16; i++) {
        int r = r0 + i;
        out[(size_t)(jb * 64 + r) * rows + kb * 64 + c] = f2bf(tile[c][r]);
    }
}

__global__ __launch_bounds__(256) void k_init_hbf(const float* __restrict__ state,
                                                  unsigned short* __restrict__ hinit) {
    int i = blockIdx.x * 256 + threadIdx.x;
    if (i < BATCH * HIDDEN) hinit[i] = f2bf(state[i]);
}

// ---------------- persistent recurrence kernel (r9-proven, 871 us) ----------------
// 128 blocks x 64 threads (1 wave each). group g = bid>>6 owns batches [g*16,+16);
// block owns j-cols [jsl*16,+16). Weights in LDS (96 KB of MFMA B-fragments).
// Exchange buffers ROTATE per step (write-once): rh -> rhall[t], h -> hall[t]
// (hall doubles as the GEMM A matrix); consumers use plain cached loads (first
// touch after poll; cross-replay residue identical -> safe).
// Producers write through (sc0 sc1), drain vmcnt(0), then all 64 lanes push the
// tag directly into the 64 consumers' PRIVATE mailbox slots (agent-scope).
// Each consumer polls only its own 256B row (1 poller/line, no contention).
// All spins watchdog-capped: protocol failure = wrong absmax, never a hang.

#define WAIT_VM0 asm volatile("s_waitcnt vmcnt(0)" ::: "memory")
#define LGKM0    asm volatile("s_waitcnt lgkmcnt(0)" ::: "memory")

#define ST8_WT(P, V) \
    asm volatile("global_store_dwordx2 %0, %1, off sc0 sc1" ::"v"(P), "v"(V) : "memory")

__device__ __forceinline__ void row_poll(const unsigned int* row, unsigned int tag) {
    const unsigned int* p = row + (threadIdx.x & 63);
    int guard = 0;
    while (true) {
        unsigned int v = __hip_atomic_load(p, __ATOMIC_RELAXED, __HIP_MEMORY_SCOPE_AGENT);
        if (__all((int)(v >= tag))) break;
        if (++guard > 8192) break;  // watchdog (never trips when healthy — r9)
        __builtin_amdgcn_s_sleep(1);
    }
}

__global__ __launch_bounds__(64, 1) void k_rnn(const int* __restrict__ x,
                                               const float* __restrict__ state,
                                               const unsigned short* __restrict__ wrt,
                                               const unsigned short* __restrict__ wzt,
                                               const unsigned short* __restrict__ wht,
                                               const float* __restrict__ W_xr, const float* __restrict__ b_r,
                                               const float* __restrict__ W_xz, const float* __restrict__ b_z,
                                               const float* __restrict__ W_xh, const float* __restrict__ b_h,
                                               const unsigned short* __restrict__ hinit, // [32][1024]
                                               unsigned short* __restrict__ hall,        // [128][32][1024]
                                               unsigned short* __restrict__ rhall,       // [128][32][1024]
                                               float* __restrict__ hstate_out,           // [32][1024]
                                               unsigned int* __restrict__ mbox) {        // [2][64][64]
    const int bid = blockIdx.x;
    const int g   = bid >> 6;
    const int jsl = bid & 63;
    const int j0  = jsl * 16;
    const int b0  = g * 16;
    const int l   = threadIdx.x;  // 0..63
    const int llo = l & 15;
    const int lhi = l >> 4;
    const int jg  = j0 + llo;

    unsigned int* gm           = mbox + g * 64 * 64;  // this group's mailbox block
    const unsigned int* myrow  = gm + jsl * 64;       // my private row (poll target)
    unsigned int* pushtgt      = gm + l * 64 + jsl;   // lane l pushes to consumer l

    __shared__ short8v wlds[3][32][64];      // 96 KB: [mat][k-subtile][lane]
    __shared__ int xs[16 * SEQ];             // 8 KB: own group's tokens
    __shared__ unsigned short pack[16 * 16]; // 512 B exchange tile

    // ---- one-time: weights -> LDS (B-frags), tokens -> LDS ----
#pragma unroll
    for (int i = 0; i < 32; i++) {
        const size_t off = (size_t)jg * HIDDEN + i * 32 + lhi * 8;
        wlds[0][i][l] = *(const short8v*)&wrt[off];
        wlds[1][i][l] = *(const short8v*)&wzt[off];
        wlds[2][i][l] = *(const short8v*)&wht[off];
    }
    for (int i = l; i < 16 * SEQ; i += 64)
        xs[i] = x[(size_t)(b0 + (i >> 7)) * SEQ + (i & 127)];

    const float brv = b_r[jg], bzv = b_z[jg], bhv = b_h[jg];
    float4v hO;
#pragma unroll
    for (int q = 0; q < 4; q++) hO[q] = state[(b0 + 4 * lhi + q) * HIDDEN + jg];
    LGKM0;  // LDS preload visible to own wave's reads

    for (int t = 0; t < SEQ; t++) {
        const unsigned short* hprev =
            t ? (hall + (size_t)(t - 1) * BATCH * HIDDEN) : hinit;
        unsigned short* rhp = rhall + (size_t)t * BATCH * HIDDEN;
        unsigned short* hp  = hall + (size_t)t * BATCH * HIDDEN;

        // embedding gathers issued BEFORE the poll (latency hides under it)
        int tok[4];
#pragma unroll
        for (int q = 0; q < 4; q++) tok[q] = xs[(4 * lhi + q) * SEQ + t];
        float xr[4], xz[4], xh[4];
#pragma unroll
        for (int q = 0; q < 4; q++) {
            xr[q] = W_xr[(size_t)tok[q] * HIDDEN + jg];
            xz[q] = W_xz[(size_t)tok[q] * HIDDEN + jg];
            xh[q] = W_xh[(size_t)tok[q] * HIDDEN + jg];
        }

        // ---- Phase A: wait h(t-1) via private row, compute r,z ----
        if (t) row_poll(myrow, 2u * (unsigned)t);

        short8v af[32];
#pragma unroll
        for (int i = 0; i < 32; i++)
            af[i] = *(const short8v*)&hprev[(b0 + llo) * HIDDEN + i * 32 + lhi * 8];

        float4v aR0 = {0.f, 0.f, 0.f, 0.f}, aR1 = {0.f, 0.f, 0.f, 0.f};
        float4v aZ0 = {0.f, 0.f, 0.f, 0.f}, aZ1 = {0.f, 0.f, 0.f, 0.f};
#pragma unroll
        for (int i = 0; i < 32; i += 2) {
            aR0 = __builtin_amdgcn_mfma_f32_16x16x32_bf16(af[i],     wlds[0][i][l],     aR0, 0, 0, 0);
            aZ0 = __builtin_amdgcn_mfma_f32_16x16x32_bf16(af[i],     wlds[1][i][l],     aZ0, 0, 0, 0);
            aR1 = __builtin_amdgcn_mfma_f32_16x16x32_bf16(af[i + 1], wlds[0][i + 1][l], aR1, 0, 0, 0);
            aZ1 = __builtin_amdgcn_mfma_f32_16x16x32_bf16(af[i + 1], wlds[1][i + 1][l], aZ1, 0, 0, 0);
        }

        float4v zv;
#pragma unroll
        for (int q = 0; q < 4; q++) {
            float sr = aR0[q] + aR1[q] + xr[q] + brv;
            float sz = aZ0[q] + aZ1[q] + xz[q] + bzv;
            float rv = 1.f / (1.f + __expf(-sr));
            zv[q]    = 1.f / (1.f + __expf(-sz));
            pack[(4 * lhi + q) * 16 + llo] = f2bf(rv * hO[q]);
        }
        LGKM0;
        __builtin_amdgcn_wave_barrier();
        {   // publish rh tile: 64x8B WT stores, drain, then push tag to all consumers
            uint2v v = *(const uint2v*)&pack[(l >> 2) * 16 + (l & 3) * 4];
            ST8_WT(&rhp[(b0 + (l >> 2)) * HIDDEN + j0 + (l & 3) * 4], v);
            WAIT_VM0;
            __hip_atomic_store(pushtgt, 2u * (unsigned)t + 1u, __ATOMIC_RELAXED,
                               __HIP_MEMORY_SCOPE_AGENT);
        }

        // ---- Phase B: wait rh via private row, compute candidate + update ----
        row_poll(myrow, 2u * (unsigned)t + 1u);

        short8v ar[32];
#pragma unroll
        for (int i = 0; i < 32; i++)
            ar[i] = *(const short8v*)&rhp[(b0 + llo) * HIDDEN + i * 32 + lhi * 8];

        float4v aC0 = {0.f, 0.f, 0.f, 0.f}, aC1 = {0.f, 0.f, 0.f, 0.f};
#pragma unroll
        for (int i = 0; i < 32; i += 2) {
            aC0 = __builtin_amdgcn_mfma_f32_16x16x32_bf16(ar[i],     wlds[2][i][l],     aC0, 0, 0, 0);
            aC1 = __builtin_amdgcn_mfma_f32_16x16x32_bf16(ar[i + 1], wlds[2][i + 1][l], aC1, 0, 0, 0);
        }
#pragma unroll
        for (int q = 0; q < 4; q++) {
            float a = aC0[q] + aC1[q] + xh[q] + bhv;
            a = fminf(15.f, fmaxf(-15.f, a));
            float e2   = __expf(2.f * a);
            float cand = (e2 - 1.f) / (e2 + 1.f);
            float hn   = zv[q] * hO[q] + (1.f - zv[q]) * cand;
            hO[q]      = hn;
            pack[(4 * lhi + q) * 16 + llo] = f2bf(hn);
        }
        LGKM0;
        __builtin_amdgcn_wave_barrier();
        {   // publish h tile into hall[t] (also the GEMM A matrix)
            uint2v v = *(const uint2v*)&pack[(l >> 2) * 16 + (l & 3) * 4];
            ST8_WT(&hp[(b0 + (l >> 2)) * HIDDEN + j0 + (l & 3) * 4], v);
            WAIT_VM0;
            __hip_atomic_store(pushtgt, 2u * (unsigned)t + 2u, __ATOMIC_RELAXED,
                               __HIP_MEMORY_SCOPE_AGENT);
        }
    }

#pragma unroll
    for (int q = 0; q < 4; q++)
        hstate_out[(b0 + 4 * lhi + q) * HIDDEN + jg] = hO[q];
}

// ---------------- output-projection GEMM ----------------
// Out[4096][32000] = hall @ bt^T + b_o, fp32 out via NON-TEMPORAL stores so the
// 512 MB out-stream does not evict bt (65 MB) + hall (8 MB) from L3.
#define BM 128
#define BN 128
#define BK 64

__device__ __forceinline__ void gload_lds16(const void* g, void* l) {
    __builtin_amdgcn_global_load_lds((const __attribute__((address_space(1))) void*)g,
                                     (__attribute__((address_space(3))) void*)l, 16, 0, 0);
}

__global__ __launch_bounds__(256, 2) void k_gemm(const unsigned short* __restrict__ A,
                                                 const unsigned short* __restrict__ B,
                                                 const float* __restrict__ bo,
                                                 float* __restrict__ out) {
    __shared__ unsigned short As[BM * BK];
    __shared__ unsigned short Bs[BN * BK];
    const int wg   = blockIdx.y * 250 + blockIdx.x;
    const int swz  = (wg & 7) * 1000 + (wg >> 3);
    const int nb   = swz % 250;
    const int mb   = swz / 250;
    const int tid  = threadIdx.x;
    const int lane = tid & 63;
    const int w    = tid >> 6;
    const int wm   = w >> 1, wn = w & 1;
    const int row0 = mb * BM, col0 = nb * BN;

    float4v acc[4][4];
#pragma unroll
    for (int i = 0; i < 4; i++)
#pragma unroll
        for (int j = 0; j < 4; j++) acc[i][j] = float4v{0.f, 0.f, 0.f, 0.f};

    for (int kt = 0; kt < HIDDEN / BK; kt++) {
#pragma unroll
        for (int i = 0; i < 4; i++) {
            int s   = i * 256 + tid;
            int row = s >> 3;
            int off = (s & 7) * 8;
            gload_lds16(A + (size_t)(row0 + row) * HIDDEN + kt * BK + off, &As[s * 8]);
            gload_lds16(B + (size_t)(col0 + row) * HIDDEN + kt * BK + off, &Bs[s * 8]);
        }
        __syncthreads();
#pragma unroll
        for (int kk = 0; kk < 2; kk++) {
            short8v af[4], bf[4];
#pragma unroll
            for (int i = 0; i < 4; i++) {
                int ar = wm * 64 + i * 16 + (lane & 15);
                af[i] = *(short8v*)&As[ar * BK + kk * 32 + (lane >> 4) * 8];
                int br = wn * 64 + i * 16 + (lane & 15);
                bf[i] = *(short8v*)&Bs[br * BK + kk * 32 + (lane >> 4) * 8];
            }
#pragma unroll
            for (int i = 0; i < 4; i++)
#pragma unroll
                for (int j = 0; j < 4; j++)
                    acc[i][j] = __builtin_amdgcn_mfma_f32_16x16x32_bf16(af[i], bf[j], acc[i][j], 0, 0, 0);
        }
        __syncthreads();
    }
#pragma unroll
    for (int i = 0; i < 4; i++) {
        int grow = row0 + wm * 64 + i * 16 + (lane >> 4) * 4;
#pragma unroll
        for (int j = 0; j < 4; j++) {
            int gcol   = col0 + wn * 64 + j * 16 + (lane & 15);
            float bias = bo[gcol];
#pragma unroll
            for (int r = 0; r < 4; r++) {
                __builtin_nontemporal_store(acc[i][j][r] + bias,
                                            &out[(size_t)(grow + r) * VOCAB + gcol]);
            }
        }
    }
}

// ---------------- host ----------------

extern "C" void kernel_launch(void* const* d_in, const int* in_sizes, int n_in,
                              void* d_out, int out_size, void* d_ws, size_t ws_size,
                              hipStream_t stream) {
    const int*   x     = (const int*)d_in[0];
    const float* state = (const float*)d_in[1];
    const float* W_xr  = (const float*)d_in[2];
    const float* W_hr  = (const float*)d_in[3];
    const float* b_r   = (const float*)d_in[4];
    const float* W_xz  = (const float*)d_in[5];
    const float* W_hz  = (const float*)d_in[6];
    const float* b_z   = (const float*)d_in[7];
    const float* W_xh  = (const float*)d_in[8];
    const float* W_hh  = (const float*)d_in[9];
    const float* b_h   = (const float*)d_in[10];
    const float* W_ho  = (const float*)d_in[11];
    const float* b_o   = (const float*)d_in[12];

    float* out    = (float*)d_out;
    float* hstate = out + (size_t)SEQ * BATCH * VOCAB;

    // ws layout (bytes):
    //   0        : hall  bf16 [128][32][1024]   8,388,608  (= GEMM A matrix)
    //   8388608  : rhall bf16 [128][32][1024]   8,388,608
    //   16777216 : bt    bf16 [32000][1024]    65,536,000
    //   82313216 : wrt   bf16 [1024][1024]      2,097,152
    //   84410368 : wzt   bf16                   2,097,152
    //   86507520 : wht   bf16                   2,097,152
    //   88604672 : hinit bf16 [32][1024]           65,536
    //   88670208 : mbox  u32  [2][64][64]          32,768   total 88,702,976
    char* ws = (char*)d_ws;
    unsigned short* hall  = (unsigned short*)ws;
    unsigned short* rhall = (unsigned short*)(ws + 8388608);
    unsigned short* bt    = (unsigned short*)(ws + 16777216);
    unsigned short* wrt   = (unsigned short*)(ws + 82313216);
    unsigned short* wzt   = (unsigned short*)(ws + 84410368);
    unsigned short* wht   = (unsigned short*)(ws + 86507520);
    unsigned short* hinit = (unsigned short*)(ws + 88604672);
    unsigned int*   mbox  = (unsigned int*)(ws + 88670208);

    hipMemsetAsync(mbox, 0, 32768, stream);
    k_transpose_bf<<<dim3(16, 16), 256, 0, stream>>>(W_hr, wrt, HIDDEN, HIDDEN);
    k_transpose_bf<<<dim3(16, 16), 256, 0, stream>>>(W_hz, wzt, HIDDEN, HIDDEN);
    k_transpose_bf<<<dim3(16, 16), 256, 0, stream>>>(W_hh, wht, HIDDEN, HIDDEN);
    k_transpose_bf<<<dim3(500, 16), 256, 0, stream>>>(W_ho, bt, VOCAB, HIDDEN);
    k_init_hbf<<<128, 256, 0, stream>>>(state, hinit);

    k_rnn<<<128, 64, 0, stream>>>(x, state, wrt, wzt, wht, W_xr, b_r, W_xz, b_z, W_xh, b_h,
                                  hinit, hall, rhall, hstate, mbox);

    k_gemm<<<dim3(250, 32), 256, 0, stream>>>(hall, bt, b_o, out);
}

// Round 13
// 1204.089 us; speedup vs baseline: 1.6604x; 1.0695x over previous
//
#include <hip/hip_runtime.h>
#include <hip/hip_bf16.h>
#include <cstdint>
#include <cstddef>

#define VOCAB 32000
#define HIDDEN 1024
#define BATCH 32
#define SEQ 128

typedef __attribute__((ext_vector_type(8))) short short8v;
typedef __attribute__((ext_vector_type(4))) float float4v;
typedef __attribute__((ext_vector_type(2))) unsigned int uint2v;

__device__ __forceinline__ unsigned short f2bf(float f) {
    unsigned int x = __float_as_uint(f);
    unsigned int r = x + 0x7fffu + ((x >> 16) & 1u);  // RNE
    return (unsigned short)(r >> 16);
}

// ---------------- pre-conversion: transpose fp32 [rows][cols] -> bf16 [cols][rows] ----------------
__global__ __launch_bounds__(256) void k_transpose_bf(const float* __restrict__ in,
                                                      unsigned short* __restrict__ out,
                                                      int cols, int rows) {
    __shared__ float tile[64][65];
    const int jb = blockIdx.x;
    const int kb = blockIdx.y;
    const int t  = threadIdx.x;
    const int c  = t & 63;
    const int r0 = (t >> 6) * 16;
#pragma unroll
    for (int i = 0; i < 16; i++) {
        int r = r0 + i;
        tile[r][c] = in[(size_t)(kb * 64 + r) * cols + jb * 64 + c];
    }
    __syncthreads();
#pragma unroll
    for (int i = 0; i < 16; i++) {
        int r = r0 + i;
        out[(size_t)(jb * 64 + r) * rows + kb * 64 + c] = f2bf(tile[c][r]);
    }
}

__global__ __launch_bounds__(256) void k_init_hbf(const float* __restrict__ state,
                                                  unsigned short* __restrict__ hinit) {
    int i = blockIdx.x * 256 + threadIdx.x;
    if (i < BATCH * HIDDEN) hinit[i] = f2bf(state[i]);
}

// ---------------- persistent recurrence kernel (r9-proven, ~875 us) ----------------

#define WAIT_VM0 asm volatile("s_waitcnt vmcnt(0)" ::: "memory")
#define LGKM0    asm volatile("s_waitcnt lgkmcnt(0)" ::: "memory")

#define ST8_WT(P, V) \
    asm volatile("global_store_dwordx2 %0, %1, off sc0 sc1" ::"v"(P), "v"(V) : "memory")

__device__ __forceinline__ void row_poll(const unsigned int* row, unsigned int tag) {
    const unsigned int* p = row + (threadIdx.x & 63);
    int guard = 0;
    while (true) {
        unsigned int v = __hip_atomic_load(p, __ATOMIC_RELAXED, __HIP_MEMORY_SCOPE_AGENT);
        if (__all((int)(v >= tag))) break;
        if (++guard > 8192) break;  // watchdog (never trips when healthy — r9)
        __builtin_amdgcn_s_sleep(1);
    }
}

__global__ __launch_bounds__(64, 1) void k_rnn(const int* __restrict__ x,
                                               const float* __restrict__ state,
                                               const unsigned short* __restrict__ wrt,
                                               const unsigned short* __restrict__ wzt,
                                               const unsigned short* __restrict__ wht,
                                               const float* __restrict__ W_xr, const float* __restrict__ b_r,
                                               const float* __restrict__ W_xz, const float* __restrict__ b_z,
                                               const float* __restrict__ W_xh, const float* __restrict__ b_h,
                                               const unsigned short* __restrict__ hinit, // [32][1024]
                                               unsigned short* __restrict__ hall,        // [128][32][1024]
                                               unsigned short* __restrict__ rhall,       // [128][32][1024]
                                               float* __restrict__ hstate_out,           // [32][1024]
                                               unsigned int* __restrict__ mbox) {        // [2][64][64]
    const int bid = blockIdx.x;
    const int g   = bid >> 6;
    const int jsl = bid & 63;
    const int j0  = jsl * 16;
    const int b0  = g * 16;
    const int l   = threadIdx.x;  // 0..63
    const int llo = l & 15;
    const int lhi = l >> 4;
    const int jg  = j0 + llo;

    unsigned int* gm           = mbox + g * 64 * 64;  // this group's mailbox block
    const unsigned int* myrow  = gm + jsl * 64;       // my private row (poll target)
    unsigned int* pushtgt      = gm + l * 64 + jsl;   // lane l pushes to consumer l

    __shared__ short8v wlds[3][32][64];      // 96 KB: [mat][k-subtile][lane]
    __shared__ int xs[16 * SEQ];             // 8 KB: own group's tokens
    __shared__ unsigned short pack[16 * 16]; // 512 B exchange tile

    // ---- one-time: weights -> LDS (B-frags), tokens -> LDS ----
#pragma unroll
    for (int i = 0; i < 32; i++) {
        const size_t off = (size_t)jg * HIDDEN + i * 32 + lhi * 8;
        wlds[0][i][l] = *(const short8v*)&wrt[off];
        wlds[1][i][l] = *(const short8v*)&wzt[off];
        wlds[2][i][l] = *(const short8v*)&wht[off];
    }
    for (int i = l; i < 16 * SEQ; i += 64)
        xs[i] = x[(size_t)(b0 + (i >> 7)) * SEQ + (i & 127)];

    const float brv = b_r[jg], bzv = b_z[jg], bhv = b_h[jg];
    float4v hO;
#pragma unroll
    for (int q = 0; q < 4; q++) hO[q] = state[(b0 + 4 * lhi + q) * HIDDEN + jg];
    LGKM0;  // LDS preload visible to own wave's reads

    for (int t = 0; t < SEQ; t++) {
        const unsigned short* hprev =
            t ? (hall + (size_t)(t - 1) * BATCH * HIDDEN) : hinit;
        unsigned short* rhp = rhall + (size_t)t * BATCH * HIDDEN;
        unsigned short* hp  = hall + (size_t)t * BATCH * HIDDEN;

        // embedding gathers issued BEFORE the poll (latency hides under it)
        int tok[4];
#pragma unroll
        for (int q = 0; q < 4; q++) tok[q] = xs[(4 * lhi + q) * SEQ + t];
        float xr[4], xz[4], xh[4];
#pragma unroll
        for (int q = 0; q < 4; q++) {
            xr[q] = W_xr[(size_t)tok[q] * HIDDEN + jg];
            xz[q] = W_xz[(size_t)tok[q] * HIDDEN + jg];
            xh[q] = W_xh[(size_t)tok[q] * HIDDEN + jg];
        }

        // ---- Phase A: wait h(t-1) via private row, compute r,z ----
        if (t) row_poll(myrow, 2u * (unsigned)t);

        short8v af[32];
#pragma unroll
        for (int i = 0; i < 32; i++)
            af[i] = *(const short8v*)&hprev[(b0 + llo) * HIDDEN + i * 32 + lhi * 8];

        float4v aR0 = {0.f, 0.f, 0.f, 0.f}, aR1 = {0.f, 0.f, 0.f, 0.f};
        float4v aZ0 = {0.f, 0.f, 0.f, 0.f}, aZ1 = {0.f, 0.f, 0.f, 0.f};
#pragma unroll
        for (int i = 0; i < 32; i += 2) {
            aR0 = __builtin_amdgcn_mfma_f32_16x16x32_bf16(af[i],     wlds[0][i][l],     aR0, 0, 0, 0);
            aZ0 = __builtin_amdgcn_mfma_f32_16x16x32_bf16(af[i],     wlds[1][i][l],     aZ0, 0, 0, 0);
            aR1 = __builtin_amdgcn_mfma_f32_16x16x32_bf16(af[i + 1], wlds[0][i + 1][l], aR1, 0, 0, 0);
            aZ1 = __builtin_amdgcn_mfma_f32_16x16x32_bf16(af[i + 1], wlds[1][i + 1][l], aZ1, 0, 0, 0);
        }

        float4v zv;
#pragma unroll
        for (int q = 0; q < 4; q++) {
            float sr = aR0[q] + aR1[q] + xr[q] + brv;
            float sz = aZ0[q] + aZ1[q] + xz[q] + bzv;
            float rv = 1.f / (1.f + __expf(-sr));
            zv[q]    = 1.f / (1.f + __expf(-sz));
            pack[(4 * lhi + q) * 16 + llo] = f2bf(rv * hO[q]);
        }
        LGKM0;
        __builtin_amdgcn_wave_barrier();
        {   // publish rh tile: 64x8B WT stores, drain, then push tag to all consumers
            uint2v v = *(const uint2v*)&pack[(l >> 2) * 16 + (l & 3) * 4];
            ST8_WT(&rhp[(b0 + (l >> 2)) * HIDDEN + j0 + (l & 3) * 4], v);
            WAIT_VM0;
            __hip_atomic_store(pushtgt, 2u * (unsigned)t + 1u, __ATOMIC_RELAXED,
                               __HIP_MEMORY_SCOPE_AGENT);
        }

        // ---- Phase B: wait rh via private row, compute candidate + update ----
        row_poll(myrow, 2u * (unsigned)t + 1u);

        short8v ar[32];
#pragma unroll
        for (int i = 0; i < 32; i++)
            ar[i] = *(const short8v*)&rhp[(b0 + llo) * HIDDEN + i * 32 + lhi * 8];

        float4v aC0 = {0.f, 0.f, 0.f, 0.f}, aC1 = {0.f, 0.f, 0.f, 0.f};
#pragma unroll
        for (int i = 0; i < 32; i += 2) {
            aC0 = __builtin_amdgcn_mfma_f32_16x16x32_bf16(ar[i],     wlds[2][i][l],     aC0, 0, 0, 0);
            aC1 = __builtin_amdgcn_mfma_f32_16x16x32_bf16(ar[i + 1], wlds[2][i + 1][l], aC1, 0, 0, 0);
        }
#pragma unroll
        for (int q = 0; q < 4; q++) {
            float a = aC0[q] + aC1[q] + xh[q] + bhv;
            a = fminf(15.f, fmaxf(-15.f, a));
            float e2   = __expf(2.f * a);
            float cand = (e2 - 1.f) / (e2 + 1.f);
            float hn   = zv[q] * hO[q] + (1.f - zv[q]) * cand;
            hO[q]      = hn;
            pack[(4 * lhi + q) * 16 + llo] = f2bf(hn);
        }
        LGKM0;
        __builtin_amdgcn_wave_barrier();
        {   // publish h tile into hall[t] (also the GEMM A matrix)
            uint2v v = *(const uint2v*)&pack[(l >> 2) * 16 + (l & 3) * 4];
            ST8_WT(&hp[(b0 + (l >> 2)) * HIDDEN + j0 + (l & 3) * 4], v);
            WAIT_VM0;
            __hip_atomic_store(pushtgt, 2u * (unsigned)t + 2u, __ATOMIC_RELAXED,
                               __HIP_MEMORY_SCOPE_AGENT);
        }
    }

#pragma unroll
    for (int q = 0; q < 4; q++)
        hstate_out[(b0 + 4 * lhi + q) * HIDDEN + jg] = hO[q];
}

// ---------------- 256x256 8-phase output-projection GEMM ----------------
// out[4096][32000] = hall @ bt^T + b_o. 2000 blocks (16x125), 512 thr (2Mx4N waves),
// BK=64, 128 KB LDS = 2 one-K-tile buffers. Per K-tile: 4 phases = C-quadrants
// (mh,nh) in order (0,0),(0,1),(1,0),(1,1). Region liveness (all waves):
//   A-region mh dead after phase (mh?4:2); B-region nh dead after phase (nh?4:3).
// Stage mapping (1 half-tile = 128 rows = 2 gload_lds/thread per phase):
//   p1 -> kt+1 A-mh1 (buf^1), p2 -> kt+1 B-nh1 (buf^1),
//   p3 -> kt+2 A-mh0 (buf, region freed at p2), p4 -> kt+2 B-nh0 (buf, freed p3).
// Fence ledger: at kt end, outstanding <= 12 loads; vmcnt(4) retires kt+1's 4
// halves, leaves kt+2's newest 2 halves in flight. Raw s_barrier (no vmcnt(0)
// drain). Bank swizzle (T2): cb ^= (row&7)<<4 on gload_lds SOURCE + ds_read
// (involution, linear LDS dest per rule #21) -> 8 banks x 2 lanes = conflict-free.
#define GTM 16   // M tiles
#define GTN 125  // N tiles

__device__ __forceinline__ void gload_lds16(const void* g, void* l) {
    __builtin_amdgcn_global_load_lds((const __attribute__((address_space(1))) void*)g,
                                     (__attribute__((address_space(3))) void*)l, 16, 0, 0);
}

// stage one 128-row half-tile: isB=0 -> A-region `half` (rows {half*64+[0,64)} u
// {128+half*64+[0,64)}); isB=1 -> B-region `half` (rows {q*64+half*32+[0,32)}).
__device__ __forceinline__ void stage_half(const unsigned short* __restrict__ mbase,
                                           unsigned short* ldsm, int half, int isB,
                                           int kt, int tid) {
#pragma unroll
    for (int i = 0; i < 2; i++) {
        int s  = i * 512 + tid;
        int ri = s >> 3;
        int cb = (s & 7) * 16;  // byte col in [0,128)
        int rt = isB ? ((ri >> 5) * 64 + half * 32 + (ri & 31))
                     : ((ri >> 6) * 128 + half * 64 + (ri & 63));
        int cbs = cb ^ ((rt & 7) << 4);  // swizzled source col (bytes)
        gload_lds16(mbase + (size_t)rt * HIDDEN + kt * 64 + (cbs >> 1),
                    ldsm + rt * 64 + (cb >> 1));
    }
}

__global__ __launch_bounds__(512, 2) void k_gemm8(const unsigned short* __restrict__ A,
                                                  const unsigned short* __restrict__ B,
                                                  const float* __restrict__ bo,
                                                  float* __restrict__ out) {
    __shared__ unsigned short lds[2][2][256 * 64];  // 128 KB: [dbuf][A/B][row*64+col]

    const int wg   = blockIdx.x;                 // 0..1999 (2000 % 8 == 0)
    const int swz  = (wg & 7) * 250 + (wg >> 3); // XCD-aware bijective swizzle
    const int mb   = swz / GTN;
    const int nb   = swz % GTN;
    const int row0 = mb * 256, col0 = nb * 256;

    const int tid = threadIdx.x;
    const int w   = tid >> 6;
    const int wm  = w >> 2;   // 0..1
    const int wn  = w & 3;    // 0..3
    const int l   = tid & 63;
    const int llo = l & 15;
    const int lhi = l >> 4;

    const unsigned short* Ab = A + (size_t)row0 * HIDDEN;
    const unsigned short* Bb = B + (size_t)col0 * HIDDEN;

    float4v acc[8][4];
#pragma unroll
    for (int i = 0; i < 8; i++)
#pragma unroll
        for (int j = 0; j < 4; j++) acc[i][j] = float4v{0.f, 0.f, 0.f, 0.f};

    // ---- prologue: kt0 all 4 halves, kt1 first 2 halves; retire kt0 ----
    stage_half(Ab, &lds[0][0][0], 0, 0, 0, tid);
    stage_half(Bb, &lds[0][1][0], 0, 1, 0, tid);
    stage_half(Ab, &lds[0][0][0], 1, 0, 0, tid);
    stage_half(Bb, &lds[0][1][0], 1, 1, 0, tid);
    stage_half(Ab, &lds[1][0][0], 0, 0, 1, tid);
    stage_half(Bb, &lds[1][1][0], 0, 1, 1, tid);
    asm volatile("s_waitcnt vmcnt(4)" ::: "memory");
    __builtin_amdgcn_s_barrier();

    for (int kt = 0; kt < 16; kt++) {
        unsigned short* lA = &lds[kt & 1][0][0];
        unsigned short* lB = &lds[kt & 1][1][0];
        unsigned short* nA = &lds[(kt & 1) ^ 1][0][0];
        unsigned short* nB = &lds[(kt & 1) ^ 1][1][0];
        short8v afr[4][2];
        short8v bfr[2][2][2];

        // ---------- phase 1: quad(mh0, nh0); stage kt+1 A-mh1 ----------
#pragma unroll
        for (int mfq = 0; mfq < 4; mfq++)
#pragma unroll
            for (int ks = 0; ks < 2; ks++) {
                int rt = wm * 128 + mfq * 16 + llo;
                int cb = ks * 64 + lhi * 16;
                afr[mfq][ks] = *(const short8v*)&lA[rt * 64 + ((cb ^ ((rt & 7) << 4)) >> 1)];
            }
#pragma unroll
        for (int nfq = 0; nfq < 2; nfq++)
#pragma unroll
            for (int ks = 0; ks < 2; ks++) {
                int rt = wn * 64 + nfq * 16 + llo;
                int cb = ks * 64 + lhi * 16;
                bfr[0][nfq][ks] = *(const short8v*)&lB[rt * 64 + ((cb ^ ((rt & 7) << 4)) >> 1)];
            }
        if (kt + 1 < 16) stage_half(Ab, nA, 1, 0, kt + 1, tid);
        __builtin_amdgcn_s_barrier();
        __builtin_amdgcn_s_setprio(1);
#pragma unroll
        for (int mfq = 0; mfq < 4; mfq++)
#pragma unroll
            for (int nfq = 0; nfq < 2; nfq++)
#pragma unroll
                for (int ks = 0; ks < 2; ks++)
                    acc[mfq][nfq] = __builtin_amdgcn_mfma_f32_16x16x32_bf16(
                        afr[mfq][ks], bfr[0][nfq][ks], acc[mfq][nfq], 0, 0, 0);
        __builtin_amdgcn_s_setprio(0);
        __builtin_amdgcn_s_barrier();

        // ---------- phase 2: quad(mh0, nh1); stage kt+1 B-nh1 ----------
#pragma unroll
        for (int nfq = 0; nfq < 2; nfq++)
#pragma unroll
            for (int ks = 0; ks < 2; ks++) {
                int rt = wn * 64 + 32 + nfq * 16 + llo;
                int cb = ks * 64 + lhi * 16;
                bfr[1][nfq][ks] = *(const short8v*)&lB[rt * 64 + ((cb ^ ((rt & 7) << 4)) >> 1)];
            }
        if (kt + 1 < 16) stage_half(Bb, nB, 1, 1, kt + 1, tid);
        __builtin_amdgcn_s_barrier();
        __builtin_amdgcn_s_setprio(1);
#pragma unroll
        for (int mfq = 0; mfq < 4; mfq++)
#pragma unroll
            for (int nfq = 0; nfq < 2; nfq++)
#pragma unroll
                for (int ks = 0; ks < 2; ks++)
                    acc[mfq][2 + nfq] = __builtin_amdgcn_mfma_f32_16x16x32_bf16(
                        afr[mfq][ks], bfr[1][nfq][ks], acc[mfq][2 + nfq], 0, 0, 0);
        __builtin_amdgcn_s_setprio(0);
        __builtin_amdgcn_s_barrier();

        // ---------- phase 3: quad(mh1, nh0); stage kt+2 A-mh0 (region freed @p2) ----------
#pragma unroll
        for (int mfq = 0; mfq < 4; mfq++)
#pragma unroll
            for (int ks = 0; ks < 2; ks++) {
                int rt = wm * 128 + 64 + mfq * 16 + llo;
                int cb = ks * 64 + lhi * 16;
                afr[mfq][ks] = *(const short8v*)&lA[rt * 64 + ((cb ^ ((rt & 7) << 4)) >> 1)];
            }
        if (kt + 2 < 16) stage_half(Ab, lA, 0, 0, kt + 2, tid);
        __builtin_amdgcn_s_barrier();
        __builtin_amdgcn_s_setprio(1);
#pragma unroll
        for (int mfq = 0; mfq < 4; mfq++)
#pragma unroll
            for (int nfq = 0; nfq < 2; nfq++)
#pragma unroll
                for (int ks = 0; ks < 2; ks++)
                    acc[4 + mfq][nfq] = __builtin_amdgcn_mfma_f32_16x16x32_bf16(
                        afr[mfq][ks], bfr[0][nfq][ks], acc[4 + mfq][nfq], 0, 0, 0);
        __builtin_amdgcn_s_setprio(0);
        __builtin_amdgcn_s_barrier();

        // ---------- phase 4: quad(mh1, nh1); stage kt+2 B-nh0 (freed @p3); fence ----------
        if (kt + 2 < 16) stage_half(Bb, lB, 0, 1, kt + 2, tid);
        __builtin_amdgcn_s_barrier();
        __builtin_amdgcn_s_setprio(1);
#pragma unroll
        for (int mfq = 0; mfq < 4; mfq++)
#pragma unroll
            for (int nfq = 0; nfq < 2; nfq++)
#pragma unroll
                for (int ks = 0; ks < 2; ks++)
                    acc[4 + mfq][2 + nfq] = __builtin_amdgcn_mfma_f32_16x16x32_bf16(
                        afr[mfq][ks], bfr[1][nfq][ks], acc[4 + mfq][2 + nfq], 0, 0, 0);
        __builtin_amdgcn_s_setprio(0);
        if (kt + 2 < 16) {
            asm volatile("s_waitcnt vmcnt(4)" ::: "memory");  // retire kt+1's 4 halves
        } else if (kt + 1 < 16) {
            asm volatile("s_waitcnt vmcnt(0)" ::: "memory");  // tail: retire kt15 fully
        }
        __builtin_amdgcn_s_barrier();
    }

    // ---- epilogue: bias + NT store ----
#pragma unroll
    for (int mf = 0; mf < 8; mf++) {
        int grow = row0 + wm * 128 + mf * 16 + lhi * 4;
#pragma unroll
        for (int nf = 0; nf < 4; nf++) {
            int gcol   = col0 + wn * 64 + nf * 16 + llo;
            float bias = bo[gcol];
#pragma unroll
            for (int r = 0; r < 4; r++)
                __builtin_nontemporal_store(acc[mf][nf][r] + bias,
                                            &out[(size_t)(grow + r) * VOCAB + gcol]);
        }
    }
}

// ---------------- host ----------------

extern "C" void kernel_launch(void* const* d_in, const int* in_sizes, int n_in,
                              void* d_out, int out_size, void* d_ws, size_t ws_size,
                              hipStream_t stream) {
    const int*   x     = (const int*)d_in[0];
    const float* state = (const float*)d_in[1];
    const float* W_xr  = (const float*)d_in[2];
    const float* W_hr  = (const float*)d_in[3];
    const float* b_r   = (const float*)d_in[4];
    const float* W_xz  = (const float*)d_in[5];
    const float* W_hz  = (const float*)d_in[6];
    const float* b_z   = (const float*)d_in[7];
    const float* W_xh  = (const float*)d_in[8];
    const float* W_hh  = (const float*)d_in[9];
    const float* b_h   = (const float*)d_in[10];
    const float* W_ho  = (const float*)d_in[11];
    const float* b_o   = (const float*)d_in[12];

    float* out    = (float*)d_out;
    float* hstate = out + (size_t)SEQ * BATCH * VOCAB;

    // ws layout (bytes):
    //   0        : hall  bf16 [128][32][1024]   8,388,608  (= GEMM A matrix)
    //   8388608  : rhall bf16 [128][32][1024]   8,388,608
    //   16777216 : bt    bf16 [32000][1024]    65,536,000
    //   82313216 : wrt   bf16 [1024][1024]      2,097,152
    //   84410368 : wzt   bf16                   2,097,152
    //   86507520 : wht   bf16                   2,097,152
    //   88604672 : hinit bf16 [32][1024]           65,536
    //   88670208 : mbox  u32  [2][64][64]          32,768   total 88,702,976
    char* ws = (char*)d_ws;
    unsigned short* hall  = (unsigned short*)ws;
    unsigned short* rhall = (unsigned short*)(ws + 8388608);
    unsigned short* bt    = (unsigned short*)(ws + 16777216);
    unsigned short* wrt   = (unsigned short*)(ws + 82313216);
    unsigned short* wzt   = (unsigned short*)(ws + 84410368);
    unsigned short* wht   = (unsigned short*)(ws + 86507520);
    unsigned short* hinit = (unsigned short*)(ws + 88604672);
    unsigned int*   mbox  = (unsigned int*)(ws + 88670208);

    hipMemsetAsync(mbox, 0, 32768, stream);
    k_transpose_bf<<<dim3(16, 16), 256, 0, stream>>>(W_hr, wrt, HIDDEN, HIDDEN);
    k_transpose_bf<<<dim3(16, 16), 256, 0, stream>>>(W_hz, wzt, HIDDEN, HIDDEN);
    k_transpose_bf<<<dim3(16, 16), 256, 0, stream>>>(W_hh, wht, HIDDEN, HIDDEN);
    k_transpose_bf<<<dim3(500, 16), 256, 0, stream>>>(W_ho, bt, VOCAB, HIDDEN);
    k_init_hbf<<<128, 256, 0, stream>>>(state, hinit);

    k_rnn<<<128, 64, 0, stream>>>(x, state, wrt, wzt, wht, W_xr, b_r, W_xz, b_z, W_xh, b_h,
                                  hinit, hall, rhall, hstate, mbox);

    k_gemm8<<<dim3(2000), 512, 0, stream>>>(hall, bt, b_o, out);
}

// Round 14
// 1102.368 us; speedup vs baseline: 1.8136x; 1.0923x over previous
//
#include <hip/hip_runtime.h>
#include <hip/hip_bf16.h>
#include <cstdint>
#include <cstddef>

#define VOCAB 32000
#define HIDDEN 1024
#define BATCH 32
#define SEQ 128

typedef __attribute__((ext_vector_type(8))) short short8v;
typedef __attribute__((ext_vector_type(4))) float float4v;
typedef __attribute__((ext_vector_type(2))) unsigned int uint2v;

__device__ __forceinline__ unsigned short f2bf(float f) {
    unsigned int x = __float_as_uint(f);
    unsigned int r = x + 0x7fffu + ((x >> 16) & 1u);  // RNE
    return (unsigned short)(r >> 16);
}

// ---------------- fused prep: all 4 transpose-converts + state init, ONE launch ----------------
// blocks [0,8000): W_ho -> bt (500x16 tiles); [8000,8256): W_hr -> wrt;
// [8256,8512): W_hz -> wzt; [8512,8768): W_hh -> wht; [8768,8896): state -> hinit.
__global__ __launch_bounds__(256) void k_prep(const float* __restrict__ who, unsigned short* __restrict__ bt,
                                              const float* __restrict__ whr, unsigned short* __restrict__ wrt,
                                              const float* __restrict__ whz, unsigned short* __restrict__ wzt,
                                              const float* __restrict__ whh, unsigned short* __restrict__ wht,
                                              const float* __restrict__ state, unsigned short* __restrict__ hinit) {
    __shared__ float tile[64][65];
    const int b = blockIdx.x;
    const int t = threadIdx.x;
    const float* in;
    unsigned short* outp;
    int cols, jb, kb;
    if (b < 8000) {
        in = who; outp = bt; cols = VOCAB; jb = b % 500; kb = b / 500;
    } else if (b < 8256) {
        int q = b - 8000; in = whr; outp = wrt; cols = HIDDEN; jb = q & 15; kb = q >> 4;
    } else if (b < 8512) {
        int q = b - 8256; in = whz; outp = wzt; cols = HIDDEN; jb = q & 15; kb = q >> 4;
    } else if (b < 8768) {
        int q = b - 8512; in = whh; outp = wht; cols = HIDDEN; jb = q & 15; kb = q >> 4;
    } else {
        int i = (b - 8768) * 256 + t;
        if (i < BATCH * HIDDEN) hinit[i] = f2bf(state[i]);
        return;
    }
    const int c  = t & 63;
    const int r0 = (t >> 6) * 16;
#pragma unroll
    for (int i = 0; i < 16; i++) {
        int r = r0 + i;
        tile[r][c] = in[(size_t)(kb * 64 + r) * cols + jb * 64 + c];
    }
    __syncthreads();
#pragma unroll
    for (int i = 0; i < 16; i++) {
        int r = r0 + i;
        outp[(size_t)(jb * 64 + r) * HIDDEN + kb * 64 + c] = f2bf(tile[c][r]);
    }
}

// ---------------- persistent recurrence kernel (r9-proven protocol) ----------------

#define WAIT_VM0 asm volatile("s_waitcnt vmcnt(0)" ::: "memory")
#define LGKM0    asm volatile("s_waitcnt lgkmcnt(0)" ::: "memory")

#define ST8_WT(P, V) \
    asm volatile("global_store_dwordx2 %0, %1, off sc0 sc1" ::"v"(P), "v"(V) : "memory")

// 2-deep pipelined poll: keep two flag loads in flight so the sampling period
// approaches RTT/2 (each check needs only vmcnt(1), the other load stays live).
// Worst case the compiler serializes (vmcnt(0)) and this degenerates to r9's poll.
__device__ __forceinline__ void row_poll(const unsigned int* row, unsigned int tag) {
    const unsigned int* p = row + (threadIdx.x & 63);
    unsigned int a = __hip_atomic_load(p, __ATOMIC_RELAXED, __HIP_MEMORY_SCOPE_AGENT);
    int guard = 0;
    while (true) {
        unsigned int b = __hip_atomic_load(p, __ATOMIC_RELAXED, __HIP_MEMORY_SCOPE_AGENT);
        if (__all((int)(a >= tag))) break;
        a = __hip_atomic_load(p, __ATOMIC_RELAXED, __HIP_MEMORY_SCOPE_AGENT);
        if (__all((int)(b >= tag))) break;
        if (++guard > 8192) break;  // watchdog: protocol failure = wrong absmax, never a hang
    }
}

__global__ __launch_bounds__(64, 1) void k_rnn(const int* __restrict__ x,
                                               const float* __restrict__ state,
                                               const unsigned short* __restrict__ wrt,
                                               const unsigned short* __restrict__ wzt,
                                               const unsigned short* __restrict__ wht,
                                               const float* __restrict__ W_xr, const float* __restrict__ b_r,
                                               const float* __restrict__ W_xz, const float* __restrict__ b_z,
                                               const float* __restrict__ W_xh, const float* __restrict__ b_h,
                                               const unsigned short* __restrict__ hinit, // [32][1024]
                                               unsigned short* __restrict__ hall,        // [128][32][1024]
                                               unsigned short* __restrict__ rhall,       // [128][32][1024]
                                               float* __restrict__ hstate_out,           // [32][1024]
                                               unsigned int* __restrict__ mbox) {        // [2][64][64]
    const int bid = blockIdx.x;
    const int g   = bid >> 6;
    const int jsl = bid & 63;
    const int j0  = jsl * 16;
    const int b0  = g * 16;
    const int l   = threadIdx.x;  // 0..63
    const int llo = l & 15;
    const int lhi = l >> 4;
    const int jg  = j0 + llo;

    unsigned int* gm           = mbox + g * 64 * 64;  // this group's mailbox block
    const unsigned int* myrow  = gm + jsl * 64;       // my private row (poll target)
    unsigned int* pushtgt      = gm + l * 64 + jsl;   // lane l pushes to consumer l

    __shared__ short8v wlds[3][32][64];      // 96 KB: [mat][k-subtile][lane]
    __shared__ int xs[16 * SEQ];             // 8 KB: own group's tokens
    __shared__ unsigned short pack[16 * 16]; // 512 B exchange tile

    // ---- one-time: weights -> LDS (B-frags), tokens -> LDS ----
#pragma unroll
    for (int i = 0; i < 32; i++) {
        const size_t off = (size_t)jg * HIDDEN + i * 32 + lhi * 8;
        wlds[0][i][l] = *(const short8v*)&wrt[off];
        wlds[1][i][l] = *(const short8v*)&wzt[off];
        wlds[2][i][l] = *(const short8v*)&wht[off];
    }
    for (int i = l; i < 16 * SEQ; i += 64)
        xs[i] = x[(size_t)(b0 + (i >> 7)) * SEQ + (i & 127)];

    const float brv = b_r[jg], bzv = b_z[jg], bhv = b_h[jg];
    float4v hO;
#pragma unroll
    for (int q = 0; q < 4; q++) hO[q] = state[(b0 + 4 * lhi + q) * HIDDEN + jg];
    LGKM0;  // LDS preload visible to own wave's reads

    for (int t = 0; t < SEQ; t++) {
        const unsigned short* hprev =
            t ? (hall + (size_t)(t - 1) * BATCH * HIDDEN) : hinit;
        unsigned short* rhp = rhall + (size_t)t * BATCH * HIDDEN;
        unsigned short* hp  = hall + (size_t)t * BATCH * HIDDEN;

        // embedding gathers issued BEFORE the poll (latency hides under it)
        int tok[4];
#pragma unroll
        for (int q = 0; q < 4; q++) tok[q] = xs[(4 * lhi + q) * SEQ + t];
        float xr[4], xz[4], xh[4];
#pragma unroll
        for (int q = 0; q < 4; q++) {
            xr[q] = W_xr[(size_t)tok[q] * HIDDEN + jg];
            xz[q] = W_xz[(size_t)tok[q] * HIDDEN + jg];
            xh[q] = W_xh[(size_t)tok[q] * HIDDEN + jg];
        }

        // ---- Phase A: wait h(t-1) via private row, compute r,z ----
        if (t) row_poll(myrow, 2u * (unsigned)t);

        short8v af[32];
#pragma unroll
        for (int i = 0; i < 32; i++)
            af[i] = *(const short8v*)&hprev[(b0 + llo) * HIDDEN + i * 32 + lhi * 8];

        float4v aR0 = {0.f, 0.f, 0.f, 0.f}, aR1 = {0.f, 0.f, 0.f, 0.f};
        float4v aZ0 = {0.f, 0.f, 0.f, 0.f}, aZ1 = {0.f, 0.f, 0.f, 0.f};
#pragma unroll
        for (int i = 0; i < 32; i += 2) {
            aR0 = __builtin_amdgcn_mfma_f32_16x16x32_bf16(af[i],     wlds[0][i][l],     aR0, 0, 0, 0);
            aZ0 = __builtin_amdgcn_mfma_f32_16x16x32_bf16(af[i],     wlds[1][i][l],     aZ0, 0, 0, 0);
            aR1 = __builtin_amdgcn_mfma_f32_16x16x32_bf16(af[i + 1], wlds[0][i + 1][l], aR1, 0, 0, 0);
            aZ1 = __builtin_amdgcn_mfma_f32_16x16x32_bf16(af[i + 1], wlds[1][i + 1][l], aZ1, 0, 0, 0);
        }

        float4v zv;
#pragma unroll
        for (int q = 0; q < 4; q++) {
            float sr = aR0[q] + aR1[q] + xr[q] + brv;
            float sz = aZ0[q] + aZ1[q] + xz[q] + bzv;
            float rv = 1.f / (1.f + __expf(-sr));
            zv[q]    = 1.f / (1.f + __expf(-sz));
            pack[(4 * lhi + q) * 16 + llo] = f2bf(rv * hO[q]);
        }
        LGKM0;
        __builtin_amdgcn_wave_barrier();
        {   // publish rh tile: 64x8B WT stores, drain, then push tag to all consumers
            uint2v v = *(const uint2v*)&pack[(l >> 2) * 16 + (l & 3) * 4];
            ST8_WT(&rhp[(b0 + (l >> 2)) * HIDDEN + j0 + (l & 3) * 4], v);
            WAIT_VM0;
            __hip_atomic_store(pushtgt, 2u * (unsigned)t + 1u, __ATOMIC_RELAXED,
                               __HIP_MEMORY_SCOPE_AGENT);
        }

        // ---- Phase B: wait rh via private row, compute candidate + update ----
        row_poll(myrow, 2u * (unsigned)t + 1u);

        short8v ar[32];
#pragma unroll
        for (int i = 0; i < 32; i++)
            ar[i] = *(const short8v*)&rhp[(b0 + llo) * HIDDEN + i * 32 + lhi * 8];

        float4v aC0 = {0.f, 0.f, 0.f, 0.f}, aC1 = {0.f, 0.f, 0.f, 0.f};
#pragma unroll
        for (int i = 0; i < 32; i += 2) {
            aC0 = __builtin_amdgcn_mfma_f32_16x16x32_bf16(ar[i],     wlds[2][i][l],     aC0, 0, 0, 0);
            aC1 = __builtin_amdgcn_mfma_f32_16x16x32_bf16(ar[i + 1], wlds[2][i + 1][l], aC1, 0, 0, 0);
        }
#pragma unroll
        for (int q = 0; q < 4; q++) {
            float a = aC0[q] + aC1[q] + xh[q] + bhv;
            a = fminf(15.f, fmaxf(-15.f, a));
            float e2   = __expf(2.f * a);
            float cand = (e2 - 1.f) / (e2 + 1.f);
            float hn   = zv[q] * hO[q] + (1.f - zv[q]) * cand;
            hO[q]      = hn;
            pack[(4 * lhi + q) * 16 + llo] = f2bf(hn);
        }
        LGKM0;
        __builtin_amdgcn_wave_barrier();
        {   // publish h tile into hall[t] (also the GEMM A matrix)
            uint2v v = *(const uint2v*)&pack[(l >> 2) * 16 + (l & 3) * 4];
            ST8_WT(&hp[(b0 + (l >> 2)) * HIDDEN + j0 + (l & 3) * 4], v);
            WAIT_VM0;
            __hip_atomic_store(pushtgt, 2u * (unsigned)t + 2u, __ATOMIC_RELAXED,
                               __HIP_MEMORY_SCOPE_AGENT);
        }
    }

#pragma unroll
    for (int q = 0; q < 4; q++)
        hstate_out[(b0 + 4 * lhi + q) * HIDDEN + jg] = hO[q];
}

// ---------------- 256x256 8-phase output-projection GEMM (r12-proven) ----------------
#define GTM 16   // M tiles
#define GTN 125  // N tiles

__device__ __forceinline__ void gload_lds16(const void* g, void* l) {
    __builtin_amdgcn_global_load_lds((const __attribute__((address_space(1))) void*)g,
                                     (__attribute__((address_space(3))) void*)l, 16, 0, 0);
}

__device__ __forceinline__ void stage_half(const unsigned short* __restrict__ mbase,
                                           unsigned short* ldsm, int half, int isB,
                                           int kt, int tid) {
#pragma unroll
    for (int i = 0; i < 2; i++) {
        int s  = i * 512 + tid;
        int ri = s >> 3;
        int cb = (s & 7) * 16;  // byte col in [0,128)
        int rt = isB ? ((ri >> 5) * 64 + half * 32 + (ri & 31))
                     : ((ri >> 6) * 128 + half * 64 + (ri & 63));
        int cbs = cb ^ ((rt & 7) << 4);  // swizzled source col (bytes)
        gload_lds16(mbase + (size_t)rt * HIDDEN + kt * 64 + (cbs >> 1),
                    ldsm + rt * 64 + (cb >> 1));
    }
}

__global__ __launch_bounds__(512, 2) void k_gemm8(const unsigned short* __restrict__ A,
                                                  const unsigned short* __restrict__ B,
                                                  const float* __restrict__ bo,
                                                  float* __restrict__ out) {
    __shared__ unsigned short lds[2][2][256 * 64];  // 128 KB: [dbuf][A/B][row*64+col]

    const int wg   = blockIdx.x;                 // 0..1999 (2000 % 8 == 0)
    const int swz  = (wg & 7) * 250 + (wg >> 3); // XCD-aware bijective swizzle
    const int mb   = swz / GTN;
    const int nb   = swz % GTN;
    const int row0 = mb * 256, col0 = nb * 256;

    const int tid = threadIdx.x;
    const int w   = tid >> 6;
    const int wm  = w >> 2;   // 0..1
    const int wn  = w & 3;    // 0..3
    const int l   = tid & 63;
    const int llo = l & 15;
    const int lhi = l >> 4;

    const unsigned short* Ab = A + (size_t)row0 * HIDDEN;
    const unsigned short* Bb = B + (size_t)col0 * HIDDEN;

    float4v acc[8][4];
#pragma unroll
    for (int i = 0; i < 8; i++)
#pragma unroll
        for (int j = 0; j < 4; j++) acc[i][j] = float4v{0.f, 0.f, 0.f, 0.f};

    // ---- prologue: kt0 all 4 halves, kt1 first 2 halves; retire kt0 ----
    stage_half(Ab, &lds[0][0][0], 0, 0, 0, tid);
    stage_half(Bb, &lds[0][1][0], 0, 1, 0, tid);
    stage_half(Ab, &lds[0][0][0], 1, 0, 0, tid);
    stage_half(Bb, &lds[0][1][0], 1, 1, 0, tid);
    stage_half(Ab, &lds[1][0][0], 0, 0, 1, tid);
    stage_half(Bb, &lds[1][1][0], 0, 1, 1, tid);
    asm volatile("s_waitcnt vmcnt(4)" ::: "memory");
    __builtin_amdgcn_s_barrier();

    for (int kt = 0; kt < 16; kt++) {
        unsigned short* lA = &lds[kt & 1][0][0];
        unsigned short* lB = &lds[kt & 1][1][0];
        unsigned short* nA = &lds[(kt & 1) ^ 1][0][0];
        unsigned short* nB = &lds[(kt & 1) ^ 1][1][0];
        short8v afr[4][2];
        short8v bfr[2][2][2];

        // ---------- phase 1: quad(mh0, nh0); stage kt+1 A-mh1 ----------
#pragma unroll
        for (int mfq = 0; mfq < 4; mfq++)
#pragma unroll
            for (int ks = 0; ks < 2; ks++) {
                int rt = wm * 128 + mfq * 16 + llo;
                int cb = ks * 64 + lhi * 16;
                afr[mfq][ks] = *(const short8v*)&lA[rt * 64 + ((cb ^ ((rt & 7) << 4)) >> 1)];
            }
#pragma unroll
        for (int nfq = 0; nfq < 2; nfq++)
#pragma unroll
            for (int ks = 0; ks < 2; ks++) {
                int rt = wn * 64 + nfq * 16 + llo;
                int cb = ks * 64 + lhi * 16;
                bfr[0][nfq][ks] = *(const short8v*)&lB[rt * 64 + ((cb ^ ((rt & 7) << 4)) >> 1)];
            }
        if (kt + 1 < 16) stage_half(Ab, nA, 1, 0, kt + 1, tid);
        __builtin_amdgcn_s_barrier();
        __builtin_amdgcn_s_setprio(1);
#pragma unroll
        for (int mfq = 0; mfq < 4; mfq++)
#pragma unroll
            for (int nfq = 0; nfq < 2; nfq++)
#pragma unroll
                for (int ks = 0; ks < 2; ks++)
                    acc[mfq][nfq] = __builtin_amdgcn_mfma_f32_16x16x32_bf16(
                        afr[mfq][ks], bfr[0][nfq][ks], acc[mfq][nfq], 0, 0, 0);
        __builtin_amdgcn_s_setprio(0);
        __builtin_amdgcn_s_barrier();

        // ---------- phase 2: quad(mh0, nh1); stage kt+1 B-nh1 ----------
#pragma unroll
        for (int nfq = 0; nfq < 2; nfq++)
#pragma unroll
            for (int ks = 0; ks < 2; ks++) {
                int rt = wn * 64 + 32 + nfq * 16 + llo;
                int cb = ks * 64 + lhi * 16;
                bfr[1][nfq][ks] = *(const short8v*)&lB[rt * 64 + ((cb ^ ((rt & 7) << 4)) >> 1)];
            }
        if (kt + 1 < 16) stage_half(Bb, nB, 1, 1, kt + 1, tid);
        __builtin_amdgcn_s_barrier();
        __builtin_amdgcn_s_setprio(1);
#pragma unroll
        for (int mfq = 0; mfq < 4; mfq++)
#pragma unroll
            for (int nfq = 0; nfq < 2; nfq++)
#pragma unroll
                for (int ks = 0; ks < 2; ks++)
                    acc[mfq][2 + nfq] = __builtin_amdgcn_mfma_f32_16x16x32_bf16(
                        afr[mfq][ks], bfr[1][nfq][ks], acc[mfq][2 + nfq], 0, 0, 0);
        __builtin_amdgcn_s_setprio(0);
        __builtin_amdgcn_s_barrier();

        // ---------- phase 3: quad(mh1, nh0); stage kt+2 A-mh0 (region freed @p2) ----------
#pragma unroll
        for (int mfq = 0; mfq < 4; mfq++)
#pragma unroll
            for (int ks = 0; ks < 2; ks++) {
                int rt = wm * 128 + 64 + mfq * 16 + llo;
                int cb = ks * 64 + lhi * 16;
                afr[mfq][ks] = *(const short8v*)&lA[rt * 64 + ((cb ^ ((rt & 7) << 4)) >> 1)];
            }
        if (kt + 2 < 16) stage_half(Ab, lA, 0, 0, kt + 2, tid);
        __builtin_amdgcn_s_barrier();
        __builtin_amdgcn_s_setprio(1);
#pragma unroll
        for (int mfq = 0; mfq < 4; mfq++)
#pragma unroll
            for (int nfq = 0; nfq < 2; nfq++)
#pragma unroll
                for (int ks = 0; ks < 2; ks++)
                    acc[4 + mfq][nfq] = __builtin_amdgcn_mfma_f32_16x16x32_bf16(
                        afr[mfq][ks], bfr[0][nfq][ks], acc[4 + mfq][nfq], 0, 0, 0);
        __builtin_amdgcn_s_setprio(0);
        __builtin_amdgcn_s_barrier();

        // ---------- phase 4: quad(mh1, nh1); stage kt+2 B-nh0 (freed @p3); fence ----------
        if (kt + 2 < 16) stage_half(Bb, lB, 0, 1, kt + 2, tid);
        __builtin_amdgcn_s_barrier();
        __builtin_amdgcn_s_setprio(1);
#pragma unroll
        for (int mfq = 0; mfq < 4; mfq++)
#pragma unroll
            for (int nfq = 0; nfq < 2; nfq++)
#pragma unroll
                for (int ks = 0; ks < 2; ks++)
                    acc[4 + mfq][2 + nfq] = __builtin_amdgcn_mfma_f32_16x16x32_bf16(
                        afr[mfq][ks], bfr[1][nfq][ks], acc[4 + mfq][2 + nfq], 0, 0, 0);
        __builtin_amdgcn_s_setprio(0);
        if (kt + 2 < 16) {
            asm volatile("s_waitcnt vmcnt(4)" ::: "memory");  // retire kt+1's 4 halves
        } else if (kt + 1 < 16) {
            asm volatile("s_waitcnt vmcnt(0)" ::: "memory");  // tail: retire kt15 fully
        }
        __builtin_amdgcn_s_barrier();
    }

    // ---- epilogue: bias + NT store ----
#pragma unroll
    for (int mf = 0; mf < 8; mf++) {
        int grow = row0 + wm * 128 + mf * 16 + lhi * 4;
#pragma unroll
        for (int nf = 0; nf < 4; nf++) {
            int gcol   = col0 + wn * 64 + nf * 16 + llo;
            float bias = bo[gcol];
#pragma unroll
            for (int r = 0; r < 4; r++)
                __builtin_nontemporal_store(acc[mf][nf][r] + bias,
                                            &out[(size_t)(grow + r) * VOCAB + gcol]);
        }
    }
}

// ---------------- host ----------------

extern "C" void kernel_launch(void* const* d_in, const int* in_sizes, int n_in,
                              void* d_out, int out_size, void* d_ws, size_t ws_size,
                              hipStream_t stream) {
    const int*   x     = (const int*)d_in[0];
    const float* state = (const float*)d_in[1];
    const float* W_xr  = (const float*)d_in[2];
    const float* W_hr  = (const float*)d_in[3];
    const float* b_r   = (const float*)d_in[4];
    const float* W_xz  = (const float*)d_in[5];
    const float* W_hz  = (const float*)d_in[6];
    const float* b_z   = (const float*)d_in[7];
    const float* W_xh  = (const float*)d_in[8];
    const float* W_hh  = (const float*)d_in[9];
    const float* b_h   = (const float*)d_in[10];
    const float* W_ho  = (const float*)d_in[11];
    const float* b_o   = (const float*)d_in[12];

    float* out    = (float*)d_out;
    float* hstate = out + (size_t)SEQ * BATCH * VOCAB;

    // ws layout (bytes):
    //   0        : hall  bf16 [128][32][1024]   8,388,608  (= GEMM A matrix)
    //   8388608  : rhall bf16 [128][32][1024]   8,388,608
    //   16777216 : bt    bf16 [32000][1024]    65,536,000
    //   82313216 : wrt   bf16 [1024][1024]      2,097,152
    //   84410368 : wzt   bf16                   2,097,152
    //   86507520 : wht   bf16                   2,097,152
    //   88604672 : hinit bf16 [32][1024]           65,536
    //   88670208 : mbox  u32  [2][64][64]          32,768   total 88,702,976
    char* ws = (char*)d_ws;
    unsigned short* hall  = (unsigned short*)ws;
    unsigned short* rhall = (unsigned short*)(ws + 8388608);
    unsigned short* bt    = (unsigned short*)(ws + 16777216);
    unsigned short* wrt   = (unsigned short*)(ws + 82313216);
    unsigned short* wzt   = (unsigned short*)(ws + 84410368);
    unsigned short* wht   = (unsigned short*)(ws + 86507520);
    unsigned short* hinit = (unsigned short*)(ws + 88604672);
    unsigned int*   mbox  = (unsigned int*)(ws + 88670208);

    hipMemsetAsync(mbox, 0, 32768, stream);
    k_prep<<<8896, 256, 0, stream>>>(W_ho, bt, W_hr, wrt, W_hz, wzt, W_hh, wht, state, hinit);

    k_rnn<<<128, 64, 0, stream>>>(x, state, wrt, wzt, wht, W_xr, b_r, W_xz, b_z, W_xh, b_h,
                                  hinit, hall, rhall, hstate, mbox);

    k_gemm8<<<dim3(2000), 512, 0, stream>>>(hall, bt, b_o, out);
}

// Round 15
// 1081.606 us; speedup vs baseline: 1.8484x; 1.0192x over previous
//
#include <hip/hip_runtime.h>
#include <hip/hip_bf16.h>
#include <cstdint>
#include <cstddef>

#define VOCAB 32000
#define HIDDEN 1024
#define BATCH 32
#define SEQ 128

typedef __attribute__((ext_vector_type(8))) short short8v;
typedef __attribute__((ext_vector_type(4))) float float4v;
typedef __attribute__((ext_vector_type(2))) unsigned int uint2v;

__device__ __forceinline__ unsigned short f2bf(float f) {
    unsigned int x = __float_as_uint(f);
    unsigned int r = x + 0x7fffu + ((x >> 16) & 1u);  // RNE
    return (unsigned short)(r >> 16);
}

// ---------------- small prep: 3 HxH transpose-converts + state init (one launch) ----------------
// blocks [0,256): W_hr->wrt; [256,512): W_hz->wzt; [512,768): W_hh->wht; [768,896): state->hinit.
__global__ __launch_bounds__(256) void k_prep(const float* __restrict__ whr, unsigned short* __restrict__ wrt,
                                              const float* __restrict__ whz, unsigned short* __restrict__ wzt,
                                              const float* __restrict__ whh, unsigned short* __restrict__ wht,
                                              const float* __restrict__ state, unsigned short* __restrict__ hinit) {
    const int b = blockIdx.x;
    const int t = threadIdx.x;
    if (b >= 768) {
        int i = (b - 768) * 256 + t;
        if (i < BATCH * HIDDEN) hinit[i] = f2bf(state[i]);
        return;
    }
    __shared__ float tile[64][65];
    const float* in    = (b < 256) ? whr : (b < 512) ? whz : whh;
    unsigned short* op = (b < 256) ? wrt : (b < 512) ? wzt : wht;
    const int q  = b & 255;
    const int jb = q & 15, kb = q >> 4;
    const int c  = t & 63;
    const int r0 = (t >> 6) * 16;
#pragma unroll
    for (int i = 0; i < 16; i++) {
        int r = r0 + i;
        tile[r][c] = in[(size_t)(kb * 64 + r) * HIDDEN + jb * 64 + c];
    }
    __syncthreads();
#pragma unroll
    for (int i = 0; i < 16; i++) {
        int r = r0 + i;
        op[(size_t)(jb * 64 + r) * HIDDEN + kb * 64 + c] = f2bf(tile[c][r]);
    }
}

// ---------------- persistent recurrence kernel + co-resident bt-transpose ----------------
// 628 blocks x 256 threads. Blocks 0..127: WORKERS (wave 0 only; threads 64..255
// exit) running the r9/r13-proven exchange protocol (107 KB LDS -> 1 block/CU).
// Blocks 128..627: LDS-FREE bt-transpose (W_ho fp32 [1024][32000] -> bt bf16
// [32000][1024]), 64 n-cols per block, wave w handles k in [w*256,+256): per-8-k
// coalesced 256B loads, packed short8v store per lane. These run on the 128 CUs
// the recurrence leaves idle (~1 TB/s for ~35 us, 4x below r10's poison level)
// and retire unconditionally (no waits -> no deadlock under any dispatch order;
// workers tolerate residency delay via the ~1 ms watchdog). bt is consumed only
// by the NEXT dispatch (k_gemm8) -> dispatch-boundary visibility (proven).

#define WAIT_VM0 asm volatile("s_waitcnt vmcnt(0)" ::: "memory")
#define LGKM0    asm volatile("s_waitcnt lgkmcnt(0)" ::: "memory")

#define ST8_WT(P, V) \
    asm volatile("global_store_dwordx2 %0, %1, off sc0 sc1" ::"v"(P), "v"(V) : "memory")

// 2-deep pipelined poll (r13-proven): two flag loads in flight -> sampling
// period ~RTT/2. Watchdog-capped: protocol failure = wrong absmax, never a hang.
__device__ __forceinline__ void row_poll(const unsigned int* row, unsigned int tag) {
    const unsigned int* p = row + (threadIdx.x & 63);
    unsigned int a = __hip_atomic_load(p, __ATOMIC_RELAXED, __HIP_MEMORY_SCOPE_AGENT);
    int guard = 0;
    while (true) {
        unsigned int b = __hip_atomic_load(p, __ATOMIC_RELAXED, __HIP_MEMORY_SCOPE_AGENT);
        if (__all((int)(a >= tag))) break;
        a = __hip_atomic_load(p, __ATOMIC_RELAXED, __HIP_MEMORY_SCOPE_AGENT);
        if (__all((int)(b >= tag))) break;
        if (++guard > 8192) break;
    }
}

__global__ __launch_bounds__(256, 1) void k_rnn(const int* __restrict__ x,
                                                const float* __restrict__ state,
                                                const unsigned short* __restrict__ wrt,
                                                const unsigned short* __restrict__ wzt,
                                                const unsigned short* __restrict__ wht,
                                                const float* __restrict__ W_xr, const float* __restrict__ b_r,
                                                const float* __restrict__ W_xz, const float* __restrict__ b_z,
                                                const float* __restrict__ W_xh, const float* __restrict__ b_h,
                                                const unsigned short* __restrict__ hinit, // [32][1024]
                                                unsigned short* __restrict__ hall,        // [128][32][1024]
                                                unsigned short* __restrict__ rhall,       // [128][32][1024]
                                                float* __restrict__ hstate_out,           // [32][1024]
                                                unsigned int* __restrict__ mbox,          // [2][64][64]
                                                const float* __restrict__ who,            // [1024][32000]
                                                unsigned short* __restrict__ bt) {        // [32000][1024]
    const int bid = blockIdx.x;

    __shared__ short8v wlds[3][32][64];      // 96 KB: [mat][k-subtile][lane]
    __shared__ int xs[16 * SEQ];             // 8 KB: own group's tokens
    __shared__ unsigned short pack[16 * 16]; // 512 B exchange tile

    if (bid >= 128) {
        // ---------- bt-transpose role (LDS-free, all 4 waves) ----------
        const int n = (bid - 128) * 64 + (threadIdx.x & 63);
        const int w4 = threadIdx.x >> 6;
        for (int k0 = w4 * 256; k0 < w4 * 256 + 256; k0 += 8) {
            short8v v;
#pragma unroll
            for (int e = 0; e < 8; e++)
                v[e] = (short)f2bf(who[(size_t)(k0 + e) * VOCAB + n]);
            *(short8v*)&bt[(size_t)n * HIDDEN + k0] = v;
        }
        return;
    }
    if (threadIdx.x >= 64) return;  // workers: wave 0 only (r10-proven pattern)

    const int g   = bid >> 6;
    const int jsl = bid & 63;
    const int j0  = jsl * 16;
    const int b0  = g * 16;
    const int l   = threadIdx.x;  // 0..63
    const int llo = l & 15;
    const int lhi = l >> 4;
    const int jg  = j0 + llo;

    unsigned int* gm           = mbox + g * 64 * 64;  // this group's mailbox block
    const unsigned int* myrow  = gm + jsl * 64;       // my private row (poll target)
    unsigned int* pushtgt      = gm + l * 64 + jsl;   // lane l pushes to consumer l

    // ---- one-time: weights -> LDS (B-frags), tokens -> LDS ----
#pragma unroll
    for (int i = 0; i < 32; i++) {
        const size_t off = (size_t)jg * HIDDEN + i * 32 + lhi * 8;
        wlds[0][i][l] = *(const short8v*)&wrt[off];
        wlds[1][i][l] = *(const short8v*)&wzt[off];
        wlds[2][i][l] = *(const short8v*)&wht[off];
    }
    for (int i = l; i < 16 * SEQ; i += 64)
        xs[i] = x[(size_t)(b0 + (i >> 7)) * SEQ + (i & 127)];

    const float brv = b_r[jg], bzv = b_z[jg], bhv = b_h[jg];
    float4v hO;
#pragma unroll
    for (int q = 0; q < 4; q++) hO[q] = state[(b0 + 4 * lhi + q) * HIDDEN + jg];
    LGKM0;  // LDS preload visible to own wave's reads

    for (int t = 0; t < SEQ; t++) {
        const unsigned short* hprev =
            t ? (hall + (size_t)(t - 1) * BATCH * HIDDEN) : hinit;
        unsigned short* rhp = rhall + (size_t)t * BATCH * HIDDEN;
        unsigned short* hp  = hall + (size_t)t * BATCH * HIDDEN;

        // embedding gathers issued BEFORE the poll (latency hides under it)
        int tok[4];
#pragma unroll
        for (int q = 0; q < 4; q++) tok[q] = xs[(4 * lhi + q) * SEQ + t];
        float xr[4], xz[4], xh[4];
#pragma unroll
        for (int q = 0; q < 4; q++) {
            xr[q] = W_xr[(size_t)tok[q] * HIDDEN + jg];
            xz[q] = W_xz[(size_t)tok[q] * HIDDEN + jg];
            xh[q] = W_xh[(size_t)tok[q] * HIDDEN + jg];
        }

        // ---- Phase A: wait h(t-1) via private row, compute r,z ----
        if (t) row_poll(myrow, 2u * (unsigned)t);

        short8v af[32];
#pragma unroll
        for (int i = 0; i < 32; i++)
            af[i] = *(const short8v*)&hprev[(b0 + llo) * HIDDEN + i * 32 + lhi * 8];

        float4v aR0 = {0.f, 0.f, 0.f, 0.f}, aR1 = {0.f, 0.f, 0.f, 0.f};
        float4v aZ0 = {0.f, 0.f, 0.f, 0.f}, aZ1 = {0.f, 0.f, 0.f, 0.f};
#pragma unroll
        for (int i = 0; i < 32; i += 2) {
            aR0 = __builtin_amdgcn_mfma_f32_16x16x32_bf16(af[i],     wlds[0][i][l],     aR0, 0, 0, 0);
            aZ0 = __builtin_amdgcn_mfma_f32_16x16x32_bf16(af[i],     wlds[1][i][l],     aZ0, 0, 0, 0);
            aR1 = __builtin_amdgcn_mfma_f32_16x16x32_bf16(af[i + 1], wlds[0][i + 1][l], aR1, 0, 0, 0);
            aZ1 = __builtin_amdgcn_mfma_f32_16x16x32_bf16(af[i + 1], wlds[1][i + 1][l], aZ1, 0, 0, 0);
        }

        float4v zv;
#pragma unroll
        for (int q = 0; q < 4; q++) {
            float sr = aR0[q] + aR1[q] + xr[q] + brv;
            float sz = aZ0[q] + aZ1[q] + xz[q] + bzv;
            float rv = 1.f / (1.f + __expf(-sr));
            zv[q]    = 1.f / (1.f + __expf(-sz));
            pack[(4 * lhi + q) * 16 + llo] = f2bf(rv * hO[q]);
        }
        LGKM0;
        __builtin_amdgcn_wave_barrier();
        {   // publish rh tile: 64x8B WT stores, drain, then push tag to all consumers
            uint2v v = *(const uint2v*)&pack[(l >> 2) * 16 + (l & 3) * 4];
            ST8_WT(&rhp[(b0 + (l >> 2)) * HIDDEN + j0 + (l & 3) * 4], v);
            WAIT_VM0;
            __hip_atomic_store(pushtgt, 2u * (unsigned)t + 1u, __ATOMIC_RELAXED,
                               __HIP_MEMORY_SCOPE_AGENT);
        }

        // ---- Phase B: wait rh via private row, compute candidate + update ----
        row_poll(myrow, 2u * (unsigned)t + 1u);

        short8v ar[32];
#pragma unroll
        for (int i = 0; i < 32; i++)
            ar[i] = *(const short8v*)&rhp[(b0 + llo) * HIDDEN + i * 32 + lhi * 8];

        float4v aC0 = {0.f, 0.f, 0.f, 0.f}, aC1 = {0.f, 0.f, 0.f, 0.f};
#pragma unroll
        for (int i = 0; i < 32; i += 2) {
            aC0 = __builtin_amdgcn_mfma_f32_16x16x32_bf16(ar[i],     wlds[2][i][l],     aC0, 0, 0, 0);
            aC1 = __builtin_amdgcn_mfma_f32_16x16x32_bf16(ar[i + 1], wlds[2][i + 1][l], aC1, 0, 0, 0);
        }
#pragma unroll
        for (int q = 0; q < 4; q++) {
            float a = aC0[q] + aC1[q] + xh[q] + bhv;
            a = fminf(15.f, fmaxf(-15.f, a));
            float e2   = __expf(2.f * a);
            float cand = (e2 - 1.f) / (e2 + 1.f);
            float hn   = zv[q] * hO[q] + (1.f - zv[q]) * cand;
            hO[q]      = hn;
            pack[(4 * lhi + q) * 16 + llo] = f2bf(hn);
        }
        LGKM0;
        __builtin_amdgcn_wave_barrier();
        {   // publish h tile into hall[t] (also the GEMM A matrix)
            uint2v v = *(const uint2v*)&pack[(l >> 2) * 16 + (l & 3) * 4];
            ST8_WT(&hp[(b0 + (l >> 2)) * HIDDEN + j0 + (l & 3) * 4], v);
            WAIT_VM0;
            __hip_atomic_store(pushtgt, 2u * (unsigned)t + 2u, __ATOMIC_RELAXED,
                               __HIP_MEMORY_SCOPE_AGENT);
        }
    }

#pragma unroll
    for (int q = 0; q < 4; q++)
        hstate_out[(b0 + 4 * lhi + q) * HIDDEN + jg] = hO[q];
}

// ---------------- 256x256 8-phase output-projection GEMM (r12-proven) ----------------
#define GTM 16   // M tiles
#define GTN 125  // N tiles

__device__ __forceinline__ void gload_lds16(const void* g, void* l) {
    __builtin_amdgcn_global_load_lds((const __attribute__((address_space(1))) void*)g,
                                     (__attribute__((address_space(3))) void*)l, 16, 0, 0);
}

__device__ __forceinline__ void stage_half(const unsigned short* __restrict__ mbase,
                                           unsigned short* ldsm, int half, int isB,
                                           int kt, int tid) {
#pragma unroll
    for (int i = 0; i < 2; i++) {
        int s  = i * 512 + tid;
        int ri = s >> 3;
        int cb = (s & 7) * 16;  // byte col in [0,128)
        int rt = isB ? ((ri >> 5) * 64 + half * 32 + (ri & 31))
                     : ((ri >> 6) * 128 + half * 64 + (ri & 63));
        int cbs = cb ^ ((rt & 7) << 4);  // swizzled source col (bytes)
        gload_lds16(mbase + (size_t)rt * HIDDEN + kt * 64 + (cbs >> 1),
                    ldsm + rt * 64 + (cb >> 1));
    }
}

__global__ __launch_bounds__(512, 2) void k_gemm8(const unsigned short* __restrict__ A,
                                                  const unsigned short* __restrict__ B,
                                                  const float* __restrict__ bo,
                                                  float* __restrict__ out) {
    __shared__ unsigned short lds[2][2][256 * 64];  // 128 KB: [dbuf][A/B][row*64+col]

    const int wg   = blockIdx.x;                 // 0..1999 (2000 % 8 == 0)
    const int swz  = (wg & 7) * 250 + (wg >> 3); // XCD-aware bijective swizzle
    const int mb   = swz / GTN;
    const int nb   = swz % GTN;
    const int row0 = mb * 256, col0 = nb * 256;

    const int tid = threadIdx.x;
    const int w   = tid >> 6;
    const int wm  = w >> 2;   // 0..1
    const int wn  = w & 3;    // 0..3
    const int l   = tid & 63;
    const int llo = l & 15;
    const int lhi = l >> 4;

    const unsigned short* Ab = A + (size_t)row0 * HIDDEN;
    const unsigned short* Bb = B + (size_t)col0 * HIDDEN;

    float4v acc[8][4];
#pragma unroll
    for (int i = 0; i < 8; i++)
#pragma unroll
        for (int j = 0; j < 4; j++) acc[i][j] = float4v{0.f, 0.f, 0.f, 0.f};

    // ---- prologue: kt0 all 4 halves, kt1 first 2 halves; retire kt0 ----
    stage_half(Ab, &lds[0][0][0], 0, 0, 0, tid);
    stage_half(Bb, &lds[0][1][0], 0, 1, 0, tid);
    stage_half(Ab, &lds[0][0][0], 1, 0, 0, tid);
    stage_half(Bb, &lds[0][1][0], 1, 1, 0, tid);
    stage_half(Ab, &lds[1][0][0], 0, 0, 1, tid);
    stage_half(Bb, &lds[1][1][0], 0, 1, 1, tid);
    asm volatile("s_waitcnt vmcnt(4)" ::: "memory");
    __builtin_amdgcn_s_barrier();

    for (int kt = 0; kt < 16; kt++) {
        unsigned short* lA = &lds[kt & 1][0][0];
        unsigned short* lB = &lds[kt & 1][1][0];
        unsigned short* nA = &lds[(kt & 1) ^ 1][0][0];
        unsigned short* nB = &lds[(kt & 1) ^ 1][1][0];
        short8v afr[4][2];
        short8v bfr[2][2][2];

        // ---------- phase 1: quad(mh0, nh0); stage kt+1 A-mh1 ----------
#pragma unroll
        for (int mfq = 0; mfq < 4; mfq++)
#pragma unroll
            for (int ks = 0; ks < 2; ks++) {
                int rt = wm * 128 + mfq * 16 + llo;
                int cb = ks * 64 + lhi * 16;
                afr[mfq][ks] = *(const short8v*)&lA[rt * 64 + ((cb ^ ((rt & 7) << 4)) >> 1)];
            }
#pragma unroll
        for (int nfq = 0; nfq < 2; nfq++)
#pragma unroll
            for (int ks = 0; ks < 2; ks++) {
                int rt = wn * 64 + nfq * 16 + llo;
                int cb = ks * 64 + lhi * 16;
                bfr[0][nfq][ks] = *(const short8v*)&lB[rt * 64 + ((cb ^ ((rt & 7) << 4)) >> 1)];
            }
        if (kt + 1 < 16) stage_half(Ab, nA, 1, 0, kt + 1, tid);
        __builtin_amdgcn_s_barrier();
        __builtin_amdgcn_s_setprio(1);
#pragma unroll
        for (int mfq = 0; mfq < 4; mfq++)
#pragma unroll
            for (int nfq = 0; nfq < 2; nfq++)
#pragma unroll
                for (int ks = 0; ks < 2; ks++)
                    acc[mfq][nfq] = __builtin_amdgcn_mfma_f32_16x16x32_bf16(
                        afr[mfq][ks], bfr[0][nfq][ks], acc[mfq][nfq], 0, 0, 0);
        __builtin_amdgcn_s_setprio(0);
        __builtin_amdgcn_s_barrier();

        // ---------- phase 2: quad(mh0, nh1); stage kt+1 B-nh1 ----------
#pragma unroll
        for (int nfq = 0; nfq < 2; nfq++)
#pragma unroll
            for (int ks = 0; ks < 2; ks++) {
                int rt = wn * 64 + 32 + nfq * 16 + llo;
                int cb = ks * 64 + lhi * 16;
                bfr[1][nfq][ks] = *(const short8v*)&lB[rt * 64 + ((cb ^ ((rt & 7) << 4)) >> 1)];
            }
        if (kt + 1 < 16) stage_half(Bb, nB, 1, 1, kt + 1, tid);
        __builtin_amdgcn_s_barrier();
        __builtin_amdgcn_s_setprio(1);
#pragma unroll
        for (int mfq = 0; mfq < 4; mfq++)
#pragma unroll
            for (int nfq = 0; nfq < 2; nfq++)
#pragma unroll
                for (int ks = 0; ks < 2; ks++)
                    acc[mfq][2 + nfq] = __builtin_amdgcn_mfma_f32_16x16x32_bf16(
                        afr[mfq][ks], bfr[1][nfq][ks], acc[mfq][2 + nfq], 0, 0, 0);
        __builtin_amdgcn_s_setprio(0);
        __builtin_amdgcn_s_barrier();

        // ---------- phase 3: quad(mh1, nh0); stage kt+2 A-mh0 (region freed @p2) ----------
#pragma unroll
        for (int mfq = 0; mfq < 4; mfq++)
#pragma unroll
            for (int ks = 0; ks < 2; ks++) {
                int rt = wm * 128 + 64 + mfq * 16 + llo;
                int cb = ks * 64 + lhi * 16;
                afr[mfq][ks] = *(const short8v*)&lA[rt * 64 + ((cb ^ ((rt & 7) << 4)) >> 1)];
            }
        if (kt + 2 < 16) stage_half(Ab, lA, 0, 0, kt + 2, tid);
        __builtin_amdgcn_s_barrier();
        __builtin_amdgcn_s_setprio(1);
#pragma unroll
        for (int mfq = 0; mfq < 4; mfq++)
#pragma unroll
            for (int nfq = 0; nfq < 2; nfq++)
#pragma unroll
                for (int ks = 0; ks < 2; ks++)
                    acc[4 + mfq][nfq] = __builtin_amdgcn_mfma_f32_16x16x32_bf16(
                        afr[mfq][ks], bfr[0][nfq][ks], acc[4 + mfq][nfq], 0, 0, 0);
        __builtin_amdgcn_s_setprio(0);
        __builtin_amdgcn_s_barrier();

        // ---------- phase 4: quad(mh1, nh1); stage kt+2 B-nh0 (freed @p3); fence ----------
        if (kt + 2 < 16) stage_half(Bb, lB, 0, 1, kt + 2, tid);
        __builtin_amdgcn_s_barrier();
        __builtin_amdgcn_s_setprio(1);
#pragma unroll
        for (int mfq = 0; mfq < 4; mfq++)
#pragma unroll
            for (int nfq = 0; nfq < 2; nfq++)
#pragma unroll
                for (int ks = 0; ks < 2; ks++)
                    acc[4 + mfq][2 + nfq] = __builtin_amdgcn_mfma_f32_16x16x32_bf16(
                        afr[mfq][ks], bfr[1][nfq][ks], acc[4 + mfq][2 + nfq], 0, 0, 0);
        __builtin_amdgcn_s_setprio(0);
        if (kt + 2 < 16) {
            asm volatile("s_waitcnt vmcnt(4)" ::: "memory");  // retire kt+1's 4 halves
        } else if (kt + 1 < 16) {
            asm volatile("s_waitcnt vmcnt(0)" ::: "memory");  // tail: retire kt15 fully
        }
        __builtin_amdgcn_s_barrier();
    }

    // ---- epilogue: bias + NT store ----
#pragma unroll
    for (int mf = 0; mf < 8; mf++) {
        int grow = row0 + wm * 128 + mf * 16 + lhi * 4;
#pragma unroll
        for (int nf = 0; nf < 4; nf++) {
            int gcol   = col0 + wn * 64 + nf * 16 + llo;
            float bias = bo[gcol];
#pragma unroll
            for (int r = 0; r < 4; r++)
                __builtin_nontemporal_store(acc[mf][nf][r] + bias,
                                            &out[(size_t)(grow + r) * VOCAB + gcol]);
        }
    }
}

// ---------------- host ----------------

extern "C" void kernel_launch(void* const* d_in, const int* in_sizes, int n_in,
                              void* d_out, int out_size, void* d_ws, size_t ws_size,
                              hipStream_t stream) {
    const int*   x     = (const int*)d_in[0];
    const float* state = (const float*)d_in[1];
    const float* W_xr  = (const float*)d_in[2];
    const float* W_hr  = (const float*)d_in[3];
    const float* b_r   = (const float*)d_in[4];
    const float* W_xz  = (const float*)d_in[5];
    const float* W_hz  = (const float*)d_in[6];
    const float* b_z   = (const float*)d_in[7];
    const float* W_xh  = (const float*)d_in[8];
    const float* W_hh  = (const float*)d_in[9];
    const float* b_h   = (const float*)d_in[10];
    const float* W_ho  = (const float*)d_in[11];
    const float* b_o   = (const float*)d_in[12];

    float* out    = (float*)d_out;
    float* hstate = out + (size_t)SEQ * BATCH * VOCAB;

    // ws layout (bytes):
    //   0        : hall  bf16 [128][32][1024]   8,388,608  (= GEMM A matrix)
    //   8388608  : rhall bf16 [128][32][1024]   8,388,608
    //   16777216 : bt    bf16 [32000][1024]    65,536,000
    //   82313216 : wrt   bf16 [1024][1024]      2,097,152
    //   84410368 : wzt   bf16                   2,097,152
    //   86507520 : wht   bf16                   2,097,152
    //   88604672 : hinit bf16 [32][1024]           65,536
    //   88670208 : mbox  u32  [2][64][64]          32,768   total 88,702,976
    char* ws = (char*)d_ws;
    unsigned short* hall  = (unsigned short*)ws;
    unsigned short* rhall = (unsigned short*)(ws + 8388608);
    unsigned short* bt    = (unsigned short*)(ws + 16777216);
    unsigned short* wrt   = (unsigned short*)(ws + 82313216);
    unsigned short* wzt   = (unsigned short*)(ws + 84410368);
    unsigned short* wht   = (unsigned short*)(ws + 86507520);
    unsigned short* hinit = (unsigned short*)(ws + 88604672);
    unsigned int*   mbox  = (unsigned int*)(ws + 88670208);

    hipMemsetAsync(mbox, 0, 32768, stream);
    k_prep<<<896, 256, 0, stream>>>(W_hr, wrt, W_hz, wzt, W_hh, wht, state, hinit);

    k_rnn<<<628, 256, 0, stream>>>(x, state, wrt, wzt, wht, W_xr, b_r, W_xz, b_z, W_xh, b_h,
                                   hinit, hall, rhall, hstate, mbox, W_ho, bt);

    k_gemm8<<<dim3(2000), 512, 0, stream>>>(hall, bt, b_o, out);
}